// Round 8
// baseline (2290.286 us; speedup 1.0000x reference)
//
#include <hip/hip_runtime.h>

// ---------------------------------------------------------------------------
// ConditionalVariationalModule: B=1024, S=256, INPUT=256, LATENT=128, HIDDEN=256
// Fused producer-consumer pipeline (single kernel, flag sync):
//   k1 part: Cq (row-aligned bf16 pairs, qm region) + Cp (row-aligned, plv region)
//   k2 part: sequential posterior scan (64 WGs); consumes cq row (b,s) then
//            overwrites it with qm output (same WG, program order) -> race-free
//   k3 part: prior MLP per (row-group, s); waits on PER-GROUP z watermarks
// Outputs (fp32): z | pm | plv | qm | qlv, each [B,S,128].
// ---------------------------------------------------------------------------

typedef __attribute__((ext_vector_type(8))) short bfrag8;   // 8 bf16 = 4 VGPR
typedef __attribute__((ext_vector_type(4))) float facc4;    // MFMA accum
typedef __attribute__((ext_vector_type(4))) unsigned int u32x4;
typedef unsigned long long ull;

#define SCOPE_AGENT __HIP_MEMORY_SCOPE_AGENT

__device__ __forceinline__ unsigned short f2bf(float x) {
  unsigned int u = __float_as_uint(x);
  u = (u + 0x7fffu + ((u >> 16) & 1u)) >> 16;   // RNE
  return (unsigned short)u;
}
__device__ __forceinline__ unsigned int pk2(float a, float b) {
  return (unsigned int)f2bf(a) | ((unsigned int)f2bf(b) << 16);
}
__device__ __forceinline__ float bf2f(unsigned int lo) {
  return __uint_as_float(lo << 16);
}
__device__ __forceinline__ facc4 mfma_bf16(bfrag8 a, bfrag8 b, facc4 c) {
  return __builtin_amdgcn_mfma_f32_16x16x32_bf16(a, b, c, 0, 0, 0);
}
__device__ __forceinline__ bfrag8 load_pin(const unsigned short* p) {
  u32x4 v = *(const u32x4*)p;
  asm volatile("" : "+v"(v));
  return __builtin_bit_cast(bfrag8, v);
}
__device__ __forceinline__ void wg_barrier() {
  asm volatile("s_waitcnt lgkmcnt(0)" ::: "memory");
  __builtin_amdgcn_sched_barrier(0);
  __builtin_amdgcn_s_barrier();
  __builtin_amdgcn_sched_barrier(0);
}
#define SWC(r, c) ((c) ^ (((r) & 8) << 1))

// ---------------------------------------------------------------------------
// Pack all 8 weight matrices into B-fragment order.
// ---------------------------------------------------------------------------
__global__ void pack_all(const float* __restrict__ qW1, const float* __restrict__ qW2,
                         const float* __restrict__ qW3, const float* __restrict__ pW1,
                         const float* __restrict__ pW2, const float* __restrict__ pW3,
                         unsigned short* __restrict__ ws) {
  int b = blockIdx.x;
  const float* src; const float* src2 = nullptr; unsigned short* dst; int KT;
  if (b < 32)       { src = qW1; src2 = qW1 + 384 * 256; dst = ws;          KT = 8; }
  else if (b < 48)  { b -= 32;  src = qW1 + 256 * 256;   dst = ws + 65536;  KT = 4; }
  else if (b < 80)  { b -= 48;  src = qW2;               dst = ws + 98304;  KT = 8; }
  else if (b < 112) { b -= 80;  src = qW3;               dst = ws + 163840; KT = 8; }
  else if (b < 144) { b -= 112; src = pW1;               dst = ws + 229376; KT = 8; }
  else if (b < 160) { b -= 144; src = pW1 + 256 * 256;   dst = ws + 294912; KT = 4; }
  else if (b < 192) { b -= 160; src = pW2;               dst = ws + 327680; KT = 8; }
  else              { b -= 192; src = pW3;               dst = ws + 393216; KT = 8; }
  int t = b * 256 + (int)threadIdx.x;
  if (t >= 16 * KT * 64) return;
  int l  = t & 63;
  int kt = (t >> 6) % KT;
  int nt = t / (64 * KT);
  int n  = nt * 16 + (l & 15);
  int k0 = kt * 32 + (l >> 4) * 8;
  unsigned int o[4];
#pragma unroll
  for (int p = 0; p < 4; ++p) {
    float a = src[(size_t)(k0 + 2 * p) * 256 + n];
    float c = src[(size_t)(k0 + 2 * p + 1) * 256 + n];
    if (src2) {
      a += src2[(size_t)(k0 + 2 * p) * 256 + n];
      c += src2[(size_t)(k0 + 2 * p + 1) * 256 + n];
    }
    o[p] = pk2(a, c);
  }
  *(uint4*)(dst + (size_t)t * 8) = make_uint4(o[0], o[1], o[2], o[3]);
}

// ---------------------------------------------------------------------------
// K1 body: one (gp, s) tile with 256 threads (4 waves). xl = 32*264 shorts.
// cq layout (qm region): uint idx (b*256+s)*128 + k = pk2(col k, col k+128).
// cp layout (plv region): ull idx (b*256+s)*64 + w*16+lm.
// ---------------------------------------------------------------------------
template<bool FUSED>
__device__ __forceinline__ void k1_body(
    int gp, int s, int tid, unsigned short* xl,
    const float* __restrict__ enc, const unsigned short* __restrict__ wq,
    const unsigned short* __restrict__ wp, const float* __restrict__ qb1,
    unsigned int* __restrict__ cq, unsigned short* __restrict__ cp) {
  {
    int row = tid >> 3, c0 = (tid & 7) * 32;
    const float* sp = enc + (((size_t)(gp * 32 + row) * 256 + s) * 256 + c0);
#pragma unroll
    for (int q = 0; q < 4; ++q) {
      float4 a = *(const float4*)(sp + q * 8);
      float4 b = *(const float4*)(sp + q * 8 + 4);
      *(uint4*)(&xl[row * 264 + SWC(row, c0 + q * 8)]) =
          make_uint4(pk2(a.x, a.y), pk2(a.z, a.w), pk2(b.x, b.y), pk2(b.z, b.w));
    }
  }
  __syncthreads();
  const int w = tid >> 6, l = tid & 63, lm = l & 15, lg = l >> 4;
  const int rr = lg * 4;
  const int nt[4] = {2 * w, 2 * w + 1, 2 * w + 8, 2 * w + 9};
  facc4 aq[2][4], ap[2][4];
#pragma unroll
  for (int j = 0; j < 4; ++j) {
    float bv = qb1[nt[j] * 16 + lm];
    aq[0][j] = (facc4){bv, bv, bv, bv}; aq[1][j] = aq[0][j];
    ap[0][j] = (facc4){0.f, 0.f, 0.f, 0.f}; ap[1][j] = ap[0][j];
  }
#pragma unroll
  for (int kt = 0; kt < 8; ++kt) {
    bfrag8 bq[4], bp[4];
#pragma unroll
    for (int j = 0; j < 4; ++j) {
      bq[j] = *(const bfrag8*)(wq + ((size_t)(nt[j] * 8 + kt) * 64 + l) * 8);
      bp[j] = *(const bfrag8*)(wp + ((size_t)(nt[j] * 8 + kt) * 64 + l) * 8);
    }
#pragma unroll
    for (int rt = 0; rt < 2; ++rt) {
      bfrag8 x = *(const bfrag8*)(&xl[(rt * 16 + lm) * 264 + SWC(lm, kt * 32 + lg * 8)]);
#pragma unroll
      for (int j = 0; j < 4; ++j) {
        aq[rt][j] = mfma_bf16(x, bq[j], aq[rt][j]);
        ap[rt][j] = mfma_bf16(x, bp[j], ap[rt][j]);
      }
    }
  }
#pragma unroll
  for (int rt = 0; rt < 2; ++rt) {
#pragma unroll
    for (int i = 0; i < 4; ++i) {
      int b = gp * 32 + rt * 16 + rr + i;
      size_t rb = ((size_t)b * 256 + s) * 128;     // uint row base in qm region
      unsigned int v0 = pk2(aq[rt][0][i], aq[rt][2][i]);   // cols 32w+lm / +128
      unsigned int v1 = pk2(aq[rt][1][i], aq[rt][3][i]);   // cols 32w+16+lm / +128
      ull vcp = (ull)pk2(ap[rt][0][i], ap[rt][1][i]) |
                ((ull)pk2(ap[rt][2][i], ap[rt][3][i]) << 32);
      size_t cpx = ((size_t)b * 256 + s) * 64 + w * 16 + lm;
      if (FUSED) {
        __hip_atomic_store(cq + rb + 32 * w + lm,      v0, __ATOMIC_RELAXED, SCOPE_AGENT);
        __hip_atomic_store(cq + rb + 32 * w + 16 + lm, v1, __ATOMIC_RELAXED, SCOPE_AGENT);
        __hip_atomic_store((ull*)cp + cpx, vcp, __ATOMIC_RELAXED, SCOPE_AGENT);
      } else {
        cq[rb + 32 * w + lm]      = v0;
        cq[rb + 32 * w + 16 + lm] = v1;
        ((ull*)cp)[cpx] = vcp;
      }
    }
  }
}

// ---------------------------------------------------------------------------
// K2 body: sequential scan, 512 threads, 8 waves x 2 nt {w, w+8}.
// Per-group z watermark: each wave release-adds 1 to zdone[g] per 8-step chunk.
// ---------------------------------------------------------------------------
template<bool FUSED>
__device__ __forceinline__ void k2_body(
    int g, int tid, unsigned short* zl, unsigned short* h1, unsigned short* h2,
    const float* __restrict__ prevz, const float* __restrict__ eps,
    const unsigned short* __restrict__ wU, const unsigned short* __restrict__ wW2,
    const unsigned short* __restrict__ wW3,
    const float* __restrict__ qb2, const float* __restrict__ qb3,
    const unsigned int* __restrict__ cq,
    float* __restrict__ z_o, float* __restrict__ qm_o, float* __restrict__ qlv_o,
    int* cqflag, int* zdone) {
  const int w = tid >> 6, l = tid & 63, lm = l & 15, lg = l >> 4;
  const int rr = lg * 4;
  const int c = 16 * w + lm;
  const int cc[2] = {c, 128 + c};

  bfrag8 u[2][4], w2[2][8], w3[2][8];
#pragma unroll
  for (int j = 0; j < 2; ++j) {
    const int nt = w + 8 * j;
#pragma unroll
    for (int kt = 0; kt < 4; ++kt)
      u[j][kt] = load_pin(wU + ((size_t)(nt * 4 + kt) * 64 + l) * 8);
#pragma unroll
    for (int kt = 0; kt < 8; ++kt) {
      w2[j][kt] = load_pin(wW2 + ((size_t)(nt * 8 + kt) * 64 + l) * 8);
      w3[j][kt] = load_pin(wW3 + ((size_t)(nt * 8 + kt) * 64 + l) * 8);
    }
  }
  const float b2[2] = {qb2[c], qb2[128 + c]};
  const float b3[2] = {qb3[c], qb3[128 + c]};
  {
    int row = tid >> 5, q0 = (tid & 31) * 4;
    float4 v = *(const float4*)(prevz + (size_t)(g * 16 + row) * 128 + q0);
    *(uint2*)(&zl[row * 136 + SWC(row, q0)]) = make_uint2(pk2(v.x, v.y), pk2(v.z, v.w));
  }
  if (FUSED) {
    if (tid == 0)
      while (__hip_atomic_load(&cqflag[0], __ATOMIC_ACQUIRE, SCOPE_AGENT) < 32)
        __builtin_amdgcn_s_sleep(2);
    wg_barrier();
  }
  size_t rix[4];
#pragma unroll
  for (int i = 0; i < 4; ++i)
    rix[i] = ((size_t)(g * 16 + rr + i) * 256) * 128 + c;   // + s*128 per step
  unsigned int cb[4];
#pragma unroll
  for (int i = 0; i < 4; ++i) cb[i] = cq[rix[i]];
  float ep[4];
#pragma unroll
  for (int i = 0; i < 4; ++i)
    ep[i] = eps[((size_t)(g * 16 + rr + i) * 256) * 128 + c];
  __syncthreads();

  for (int sb = 0; sb < 32; ++sb) {
    if (FUSED) {
      // publish this wave's z through step 8*sb-1 into group watermark
      if (sb > 0 && l == 0)
        __hip_atomic_fetch_add(&zdone[g], 1, __ATOMIC_RELEASE, SCOPE_AGENT);
      // wait for cq rows needed by this chunk's prefetches (sn in [8sb+1, 8sb+8])
      if (tid == 0) {
        int hi = sb * 8 + 8; if (hi > 255) hi = 255;
        for (int q = sb * 8 + 1; q <= hi; ++q)
          while (__hip_atomic_load(&cqflag[q], __ATOMIC_ACQUIRE, SCOPE_AGENT) < 32)
            __builtin_amdgcn_s_sleep(2);
      }
      wg_barrier();
    }
#pragma unroll 1
    for (int si = 0; si < 8; ++si) {
      const int s = sb * 8 + si;
      facc4 a[2];
#pragma unroll
      for (int i = 0; i < 4; ++i) {
        a[0][i] = bf2f(cb[i] & 0xffffu);
        a[1][i] = bf2f(cb[i] >> 16);
      }
      const int sn = (s + 1 < 256) ? s + 1 : s;
      unsigned int nbv[4];
#pragma unroll
      for (int i = 0; i < 4; ++i) nbv[i] = cq[rix[i] + (size_t)sn * 128];
      float epn[4];
#pragma unroll
      for (int i = 0; i < 4; ++i)
        epn[i] = eps[((size_t)(g * 16 + rr + i) * 256 + sn) * 128 + c];
      // ---- layer 1 ----
#pragma unroll
      for (int kt = 0; kt < 4; ++kt) {
        bfrag8 zf = *(const bfrag8*)(&zl[lm * 136 + SWC(lm, kt * 32 + lg * 8)]);
        a[0] = mfma_bf16(zf, u[0][kt], a[0]);
        a[1] = mfma_bf16(zf, u[1][kt], a[1]);
      }
#pragma unroll
      for (int j = 0; j < 2; ++j)
#pragma unroll
        for (int i = 0; i < 4; ++i)
          h1[(rr + i) * 264 + SWC(rr + i, cc[j])] = f2bf(fmaxf(a[j][i], 0.f));
      wg_barrier();
      // ---- layer 2 ----
      facc4 cv[2] = {(facc4){b2[0], b2[0], b2[0], b2[0]},
                     (facc4){b2[1], b2[1], b2[1], b2[1]}};
#pragma unroll
      for (int kt = 0; kt < 8; ++kt) {
        bfrag8 hf = *(const bfrag8*)(&h1[lm * 264 + SWC(lm, kt * 32 + lg * 8)]);
        cv[0] = mfma_bf16(hf, w2[0][kt], cv[0]);
        cv[1] = mfma_bf16(hf, w2[1][kt], cv[1]);
      }
#pragma unroll
      for (int j = 0; j < 2; ++j)
#pragma unroll
        for (int i = 0; i < 4; ++i)
          h2[(rr + i) * 264 + SWC(rr + i, cc[j])] = f2bf(fmaxf(cv[j][i], 0.f));
      wg_barrier();
      // ---- layer 3 + reparameterization, in-lane ----
      facc4 o[2] = {(facc4){b3[0], b3[0], b3[0], b3[0]},
                    (facc4){b3[1], b3[1], b3[1], b3[1]}};
#pragma unroll
      for (int kt = 0; kt < 8; ++kt) {
        bfrag8 hf = *(const bfrag8*)(&h2[lm * 264 + SWC(lm, kt * 32 + lg * 8)]);
        o[0] = mfma_bf16(hf, w3[0][kt], o[0]);
        o[1] = mfma_bf16(hf, w3[1][kt], o[1]);
      }
#pragma unroll
      for (int i = 0; i < 4; ++i) {
        size_t ob = ((size_t)(g * 16 + rr + i) * 256 + s) * 128;
        float zq = o[0][i] + ep[i] * __expf(0.5f * o[1][i]);
        qm_o[ob + c]  = o[0][i];     // overwrites this row's consumed cq pair
        qlv_o[ob + c] = o[1][i];
        if (FUSED)
          __hip_atomic_store(&z_o[ob + c], zq, __ATOMIC_RELAXED, SCOPE_AGENT);
        else
          z_o[ob + c] = zq;
        zl[(rr + i) * 136 + SWC(rr + i, c)] = f2bf(zq);
      }
      wg_barrier();
#pragma unroll
      for (int i = 0; i < 4; ++i) { cb[i] = nbv[i]; ep[i] = epn[i]; }
    }
  }
  if (FUSED) {
    asm volatile("s_waitcnt vmcnt(0)" ::: "memory");
    if (l == 0)
      __hip_atomic_fetch_add(&zdone[g], 1, __ATOMIC_RELEASE, SCOPE_AGENT);  // z<=255
  }
}

// ---------------------------------------------------------------------------
// K3 body: prior MLP, one (gp64, s), 256 threads. Waits on zdone[4gp..4gp+3].
// ---------------------------------------------------------------------------
template<bool FUSED>
__device__ __forceinline__ void k3_body(
    int gp, int s, int tid, unsigned short* zl, unsigned short* hb,
    const float* __restrict__ prevz, const float* __restrict__ z_in,
    const unsigned short* __restrict__ cp,
    const unsigned short* __restrict__ wU, const unsigned short* __restrict__ w2p,
    const unsigned short* __restrict__ w3p,
    const float* __restrict__ pb1, const float* __restrict__ pb2,
    const float* __restrict__ pb3,
    float* __restrict__ pm_o, float* __restrict__ plv_o,
    int* cqflag, int* zdone) {
  if (FUSED) {
    if (tid == 0) {
      while (__hip_atomic_load(&cqflag[s], __ATOMIC_ACQUIRE, SCOPE_AGENT) < 32)
        __builtin_amdgcn_s_sleep(8);
      int need = 8 * ((s + 7) >> 3);   // per-group watermark for z through s-1
      if (need) {
#pragma unroll
        for (int j = 0; j < 4; ++j)
          while (__hip_atomic_load(&zdone[4 * gp + j], __ATOMIC_ACQUIRE, SCOPE_AGENT) < need)
            __builtin_amdgcn_s_sleep(8);
      }
    }
    __syncthreads();
  }
  const int w = tid >> 6, l = tid & 63, lm = l & 15, lg = l >> 4;
  const int rr = lg * 4;
  const int nt[4] = {2 * w, 2 * w + 1, 2 * w + 8, 2 * w + 9};
  const int c0 = 32 * w + lm, c1 = c0 + 16;
  const int cc[4] = {c0, c1, 128 + c0, 128 + c1};
  {
    int row = tid >> 2, q0 = (tid & 3) * 32;
    const float* sp = (s == 0) ? (prevz + (size_t)(gp * 64 + row) * 128 + q0)
                               : (z_in + ((size_t)(gp * 64 + row) * 256 + (s - 1)) * 128 + q0);
#pragma unroll
    for (int q = 0; q < 4; ++q) {
      float4 a = *(const float4*)(sp + q * 8);
      float4 b = *(const float4*)(sp + q * 8 + 4);
      *(uint4*)(&zl[row * 136 + SWC(row, q0 + q * 8)]) =
          make_uint4(pk2(a.x, a.y), pk2(a.z, a.w), pk2(b.x, b.y), pk2(b.z, b.w));
    }
  }
  const float pb[4] = {pb1[nt[0] * 16 + lm], pb1[nt[1] * 16 + lm],
                       pb1[nt[2] * 16 + lm], pb1[nt[3] * 16 + lm]};
  facc4 acc[4][4];
#pragma unroll
  for (int rt = 0; rt < 4; ++rt)
#pragma unroll
    for (int i = 0; i < 4; ++i) {
      int b = gp * 64 + rt * 16 + rr + i;
      ull v = ((const ull*)cp)[((size_t)b * 256 + s) * 64 + w * 16 + lm];
      unsigned int vx = (unsigned int)v, vy = (unsigned int)(v >> 32);
      acc[rt][0][i] = pb[0] + bf2f(vx & 0xffffu);
      acc[rt][1][i] = pb[1] + bf2f(vx >> 16);
      acc[rt][2][i] = pb[2] + bf2f(vy & 0xffffu);
      acc[rt][3][i] = pb[3] + bf2f(vy >> 16);
    }
  __syncthreads();
  // ---- layer 1: + z @ Up ----
#pragma unroll
  for (int kt = 0; kt < 4; ++kt) {
    bfrag8 b0 = *(const bfrag8*)(wU + ((size_t)(nt[0] * 4 + kt) * 64 + l) * 8);
    bfrag8 b1 = *(const bfrag8*)(wU + ((size_t)(nt[1] * 4 + kt) * 64 + l) * 8);
    bfrag8 b2f = *(const bfrag8*)(wU + ((size_t)(nt[2] * 4 + kt) * 64 + l) * 8);
    bfrag8 b3f = *(const bfrag8*)(wU + ((size_t)(nt[3] * 4 + kt) * 64 + l) * 8);
#pragma unroll
    for (int rt = 0; rt < 4; ++rt) {
      bfrag8 zf = *(const bfrag8*)(&zl[(rt * 16 + lm) * 136 + SWC(lm, kt * 32 + lg * 8)]);
      acc[rt][0] = mfma_bf16(zf, b0, acc[rt][0]);
      acc[rt][1] = mfma_bf16(zf, b1, acc[rt][1]);
      acc[rt][2] = mfma_bf16(zf, b2f, acc[rt][2]);
      acc[rt][3] = mfma_bf16(zf, b3f, acc[rt][3]);
    }
  }
#pragma unroll
  for (int rt = 0; rt < 4; ++rt)
#pragma unroll
    for (int j = 0; j < 4; ++j)
#pragma unroll
      for (int i = 0; i < 4; ++i) {
        int r = rt * 16 + rr + i;
        hb[r * 264 + SWC(r, cc[j])] = f2bf(fmaxf(acc[rt][j][i], 0.f));
      }
  __syncthreads();
  // ---- layer 2 ----
  facc4 a2[4][4];
#pragma unroll
  for (int rt = 0; rt < 4; ++rt)
#pragma unroll
    for (int j = 0; j < 4; ++j) a2[rt][j] = (facc4){pb2[nt[j] * 16 + lm], pb2[nt[j] * 16 + lm],
                                                    pb2[nt[j] * 16 + lm], pb2[nt[j] * 16 + lm]};
#pragma unroll
  for (int kt = 0; kt < 8; ++kt) {
    bfrag8 b0 = *(const bfrag8*)(w2p + ((size_t)(nt[0] * 8 + kt) * 64 + l) * 8);
    bfrag8 b1 = *(const bfrag8*)(w2p + ((size_t)(nt[1] * 8 + kt) * 64 + l) * 8);
    bfrag8 b2f = *(const bfrag8*)(w2p + ((size_t)(nt[2] * 8 + kt) * 64 + l) * 8);
    bfrag8 b3f = *(const bfrag8*)(w2p + ((size_t)(nt[3] * 8 + kt) * 64 + l) * 8);
#pragma unroll
    for (int rt = 0; rt < 4; ++rt) {
      bfrag8 hf = *(const bfrag8*)(&hb[(rt * 16 + lm) * 264 + SWC(lm, kt * 32 + lg * 8)]);
      a2[rt][0] = mfma_bf16(hf, b0, a2[rt][0]);
      a2[rt][1] = mfma_bf16(hf, b1, a2[rt][1]);
      a2[rt][2] = mfma_bf16(hf, b2f, a2[rt][2]);
      a2[rt][3] = mfma_bf16(hf, b3f, a2[rt][3]);
    }
  }
  __syncthreads();
#pragma unroll
  for (int rt = 0; rt < 4; ++rt)
#pragma unroll
    for (int j = 0; j < 4; ++j)
#pragma unroll
      for (int i = 0; i < 4; ++i) {
        int r = rt * 16 + rr + i;
        hb[r * 264 + SWC(r, cc[j])] = f2bf(fmaxf(a2[rt][j][i], 0.f));
      }
  __syncthreads();
  // ---- layer 3 ----
  facc4 a3[4][4];
#pragma unroll
  for (int rt = 0; rt < 4; ++rt)
#pragma unroll
    for (int j = 0; j < 4; ++j) a3[rt][j] = (facc4){pb3[nt[j] * 16 + lm], pb3[nt[j] * 16 + lm],
                                                    pb3[nt[j] * 16 + lm], pb3[nt[j] * 16 + lm]};
#pragma unroll
  for (int kt = 0; kt < 8; ++kt) {
    bfrag8 b0 = *(const bfrag8*)(w3p + ((size_t)(nt[0] * 8 + kt) * 64 + l) * 8);
    bfrag8 b1 = *(const bfrag8*)(w3p + ((size_t)(nt[1] * 8 + kt) * 64 + l) * 8);
    bfrag8 b2f = *(const bfrag8*)(w3p + ((size_t)(nt[2] * 8 + kt) * 64 + l) * 8);
    bfrag8 b3f = *(const bfrag8*)(w3p + ((size_t)(nt[3] * 8 + kt) * 64 + l) * 8);
#pragma unroll
    for (int rt = 0; rt < 4; ++rt) {
      bfrag8 hf = *(const bfrag8*)(&hb[(rt * 16 + lm) * 264 + SWC(lm, kt * 32 + lg * 8)]);
      a3[rt][0] = mfma_bf16(hf, b0, a3[rt][0]);
      a3[rt][1] = mfma_bf16(hf, b1, a3[rt][1]);
      a3[rt][2] = mfma_bf16(hf, b2f, a3[rt][2]);
      a3[rt][3] = mfma_bf16(hf, b3f, a3[rt][3]);
    }
  }
#pragma unroll
  for (int rt = 0; rt < 4; ++rt)
#pragma unroll
    for (int i = 0; i < 4; ++i) {
      size_t base = ((size_t)(gp * 64 + rt * 16 + rr + i) * 256 + s) * 128;
      pm_o[base + c0]  = a3[rt][0][i];
      pm_o[base + c1]  = a3[rt][1][i];
      plv_o[base + c0] = a3[rt][2][i];
      plv_o[base + c1] = a3[rt][3][i];
    }
}

// ---------------------------------------------------------------------------
// Fused mega-kernel. Block order: k1 (4096, s-major, 2 s/block) | k2 (64) |
// k3 (4096, s-major). 512 threads. Shared-mem union = 51200 B (k3 footprint).
// ---------------------------------------------------------------------------
__global__ __launch_bounds__(512, 2) void mega(
    const float* __restrict__ enc, const float* __restrict__ prevz,
    const float* __restrict__ eps,
    const unsigned short* __restrict__ Wqe, const unsigned short* __restrict__ Uq,
    const unsigned short* __restrict__ W2q, const unsigned short* __restrict__ W3q,
    const unsigned short* __restrict__ W1ph, const unsigned short* __restrict__ Up,
    const unsigned short* __restrict__ W2p, const unsigned short* __restrict__ W3p,
    const float* __restrict__ qb1, const float* __restrict__ qb2,
    const float* __restrict__ qb3, const float* __restrict__ pb1,
    const float* __restrict__ pb2, const float* __restrict__ pb3,
    unsigned int* cq, unsigned short* cp,
    float* z_o, float* qm_o, float* qlv_o, float* pm_o, float* plv_o,
    int* cqflag, int* zdone) {
  __shared__ __align__(16) char smem[51200];
  const int bid = blockIdx.x;
  const int tid = threadIdx.x;
  if (bid < 4096) {
    // ---- k1: two s-tiles per block (one per 256-thread half) ----
    const int spair = bid >> 5, gp = bid & 31;
    const int h = tid >> 8, t = tid & 255;
    const int s = 2 * spair + h;
    unsigned short* xl = (unsigned short*)smem + h * (32 * 264);
    k1_body<true>(gp, s, t, xl, enc, Wqe, W1ph, qb1, cq, cp);
    __syncthreads();   // each wave drains vmcnt before barrier -> stores visible
    if (tid == 0) {
      __hip_atomic_fetch_add(&cqflag[2 * spair],     1, __ATOMIC_RELEASE, SCOPE_AGENT);
      __hip_atomic_fetch_add(&cqflag[2 * spair + 1], 1, __ATOMIC_RELEASE, SCOPE_AGENT);
    }
  } else if (bid < 4160) {
    // ---- k2 ----
    const int g = bid - 4096;
    unsigned short* zl = (unsigned short*)smem;
    unsigned short* h1 = zl + 16 * 136;
    unsigned short* h2 = h1 + 16 * 264;
    k2_body<true>(g, tid, zl, h1, h2, prevz, eps, Uq, W2q, W3q, qb2, qb3, cq,
                  z_o, qm_o, qlv_o, cqflag, zdone);
  } else {
    // ---- k3 ----
    if (tid >= 256) return;
    const int b2 = bid - 4160;
    const int s = b2 >> 4, gp = b2 & 15;
    unsigned short* zl = (unsigned short*)smem;
    unsigned short* hb = zl + 64 * 136;
    k3_body<true>(gp, s, tid, zl, hb, prevz, z_o, cp, Up, W2p, W3p,
                  pb1, pb2, pb3, pm_o, plv_o, cqflag, zdone);
  }
}

// ---------------------------------------------------------------------------
// Fallback sequential kernels (used if ws too small for flags).
// ---------------------------------------------------------------------------
__global__ __launch_bounds__(256, 2) void k1_pre(
    const float* __restrict__ enc, const unsigned short* __restrict__ wq,
    const unsigned short* __restrict__ wp, const float* __restrict__ qb1,
    unsigned int* __restrict__ cq, unsigned short* __restrict__ cp) {
  __shared__ unsigned short xl[32 * 264];
  k1_body<false>(blockIdx.x >> 8, blockIdx.x & 255, threadIdx.x, xl,
                 enc, wq, wp, qb1, cq, cp);
}
__global__ __launch_bounds__(512, 2) void k2_scan(
    const float* __restrict__ prevz, const float* __restrict__ eps,
    const unsigned short* __restrict__ wU, const unsigned short* __restrict__ wW2,
    const unsigned short* __restrict__ wW3,
    const float* __restrict__ qb2, const float* __restrict__ qb3,
    const unsigned int* __restrict__ cq,
    float* __restrict__ z_o, float* __restrict__ qm_o, float* __restrict__ qlv_o) {
  __shared__ unsigned short zl[16 * 136];
  __shared__ unsigned short h1[16 * 264];
  __shared__ unsigned short h2[16 * 264];
  k2_body<false>(blockIdx.x, threadIdx.x, zl, h1, h2, prevz, eps, wU, wW2, wW3,
                 qb2, qb3, cq, z_o, qm_o, qlv_o, nullptr, nullptr);
}
__global__ __launch_bounds__(256, 2) void k3_prior(
    const float* __restrict__ prevz, const float* __restrict__ z_in,
    const unsigned short* __restrict__ cp,
    const unsigned short* __restrict__ wU, const unsigned short* __restrict__ w2p,
    const unsigned short* __restrict__ w3p,
    const float* __restrict__ pb1, const float* __restrict__ pb2,
    const float* __restrict__ pb3,
    float* __restrict__ pm_o, float* __restrict__ plv_o) {
  __shared__ unsigned short zl[64 * 136];
  __shared__ unsigned short hb[64 * 264];
  k3_body<false>(blockIdx.x >> 8, blockIdx.x & 255, threadIdx.x, zl, hb,
                 prevz, z_in, cp, wU, w2p, w3p, pb1, pb2, pb3, pm_o, plv_o,
                 nullptr, nullptr);
}

// ---------------------------------------------------------------------------
extern "C" void kernel_launch(void* const* d_in, const int* in_sizes, int n_in,
                              void* d_out, int out_size, void* d_ws, size_t ws_size,
                              hipStream_t stream) {
  const float* enc   = (const float*)d_in[0];
  const float* prevz = (const float*)d_in[1];
  const float* eps   = (const float*)d_in[2];
  const float* pW1 = (const float*)d_in[3];
  const float* pb1 = (const float*)d_in[4];
  const float* pW2 = (const float*)d_in[5];
  const float* pb2 = (const float*)d_in[6];
  const float* pW3 = (const float*)d_in[7];
  const float* pb3 = (const float*)d_in[8];
  const float* qW1 = (const float*)d_in[9];
  const float* qb1 = (const float*)d_in[10];
  const float* qW2 = (const float*)d_in[11];
  const float* qb2 = (const float*)d_in[12];
  const float* qW3 = (const float*)d_in[13];
  const float* qb3 = (const float*)d_in[14];

  float* out = (float*)d_out;
  const size_t O = (size_t)1024 * 256 * 128;
  float* z_o   = out;
  float* pm_o  = out + O;
  float* plv_o = out + 2 * O;
  float* qm_o  = out + 3 * O;
  float* qlv_o = out + 4 * O;
  unsigned int*   cq = (unsigned int*)qm_o;     // row-aligned Cq pairs (k2 input;
                                                // k2 itself overwrites with qm)
  unsigned short* cp = (unsigned short*)plv_o;  // row-aligned Cp (k3 input)

  unsigned short* ws = (unsigned short*)d_ws;
  unsigned short* Wqe  = ws;             // 65536
  unsigned short* Uq   = ws + 65536;     // 32768
  unsigned short* W2q  = ws + 98304;     // 65536
  unsigned short* W3q  = ws + 163840;    // 65536
  unsigned short* W1ph = ws + 229376;    // 65536
  unsigned short* Up   = ws + 294912;    // 32768
  unsigned short* W2p  = ws + 327680;    // 65536
  unsigned short* W3p  = ws + 393216;    // 65536 (weights end: 458752 shorts)

  const size_t FLAGS_OFF = 458752u * 2u;          // bytes
  int* cqflag = (int*)((char*)d_ws + FLAGS_OFF);  // 256 ints
  int* zdone  = cqflag + 256;                     // 64 ints (per k2 group)
  const bool fused = ws_size >= FLAGS_OFF + 320 * sizeof(int);

  pack_all<<<224, 256, 0, stream>>>(qW1, qW2, qW3, pW1, pW2, pW3, ws);
  if (fused) {
    hipMemsetAsync(cqflag, 0, 320 * sizeof(int), stream);
    mega<<<8256, 512, 0, stream>>>(enc, prevz, eps,
                                   Wqe, Uq, W2q, W3q, W1ph, Up, W2p, W3p,
                                   qb1, qb2, qb3, pb1, pb2, pb3,
                                   cq, cp, z_o, qm_o, qlv_o, pm_o, plv_o,
                                   cqflag, zdone);
  } else {
    k1_pre<<<8192, 256, 0, stream>>>(enc, Wqe, W1ph, qb1, cq, cp);
    k2_scan<<<64, 512, 0, stream>>>(prevz, eps, Uq, W2q, W3q, qb2, qb3, cq,
                                    z_o, qm_o, qlv_o);
    k3_prior<<<4096, 256, 0, stream>>>(prevz, z_o, cp, Up, W2p, W3p,
                                       pb1, pb2, pb3, pm_o, plv_o);
  }
}

// Round 9
// 1724.738 us; speedup vs baseline: 1.3279x; 1.3279x over previous
//
#include <hip/hip_runtime.h>

// ---------------------------------------------------------------------------
// ConditionalVariationalModule: B=1024, S=256, INPUT=256, LATENT=128, HIDDEN=256
// Fused pipeline, CU-exclusive scan:
//   block order: k2 scan (64, dispatched FIRST) | k1 (4096) | k3 (4096)
//   84 KB dynamic LDS forces 1 block/CU -> k2 owns its CUs (no co-residency).
//   k1: Cq (row-aligned bf16 pairs, qm region) + Cp (row-aligned, plv region)
//   k2: sequential posterior scan; consumes cq row (b,s) then overwrites it
//       with qm output (same WG, program order) -> race-free
//   k3: prior MLP per (row-group, s); waits on per-group z watermarks
// Outputs (fp32): z | pm | plv | qm | qlv, each [B,S,128].
// ---------------------------------------------------------------------------

typedef __attribute__((ext_vector_type(8))) short bfrag8;   // 8 bf16 = 4 VGPR
typedef __attribute__((ext_vector_type(4))) float facc4;    // MFMA accum
typedef __attribute__((ext_vector_type(4))) unsigned int u32x4;
typedef unsigned long long ull;

#define SCOPE_AGENT __HIP_MEMORY_SCOPE_AGENT

__device__ __forceinline__ unsigned short f2bf(float x) {
  unsigned int u = __float_as_uint(x);
  u = (u + 0x7fffu + ((u >> 16) & 1u)) >> 16;   // RNE
  return (unsigned short)u;
}
__device__ __forceinline__ unsigned int pk2(float a, float b) {
  return (unsigned int)f2bf(a) | ((unsigned int)f2bf(b) << 16);
}
__device__ __forceinline__ float bf2f(unsigned int lo) {
  return __uint_as_float(lo << 16);
}
__device__ __forceinline__ facc4 mfma_bf16(bfrag8 a, bfrag8 b, facc4 c) {
  return __builtin_amdgcn_mfma_f32_16x16x32_bf16(a, b, c, 0, 0, 0);
}
__device__ __forceinline__ bfrag8 load_pin(const unsigned short* p) {
  u32x4 v = *(const u32x4*)p;
  asm volatile("" : "+v"(v));
  return __builtin_bit_cast(bfrag8, v);
}
__device__ __forceinline__ void wg_barrier() {
  asm volatile("s_waitcnt lgkmcnt(0)" ::: "memory");
  __builtin_amdgcn_sched_barrier(0);
  __builtin_amdgcn_s_barrier();
  __builtin_amdgcn_sched_barrier(0);
}
#define SWC(r, c) ((c) ^ (((r) & 8) << 1))

// ---------------------------------------------------------------------------
// Pack all 8 weight matrices into B-fragment order.
// ---------------------------------------------------------------------------
__global__ void pack_all(const float* __restrict__ qW1, const float* __restrict__ qW2,
                         const float* __restrict__ qW3, const float* __restrict__ pW1,
                         const float* __restrict__ pW2, const float* __restrict__ pW3,
                         unsigned short* __restrict__ ws) {
  int b = blockIdx.x;
  const float* src; const float* src2 = nullptr; unsigned short* dst; int KT;
  if (b < 32)       { src = qW1; src2 = qW1 + 384 * 256; dst = ws;          KT = 8; }
  else if (b < 48)  { b -= 32;  src = qW1 + 256 * 256;   dst = ws + 65536;  KT = 4; }
  else if (b < 80)  { b -= 48;  src = qW2;               dst = ws + 98304;  KT = 8; }
  else if (b < 112) { b -= 80;  src = qW3;               dst = ws + 163840; KT = 8; }
  else if (b < 144) { b -= 112; src = pW1;               dst = ws + 229376; KT = 8; }
  else if (b < 160) { b -= 144; src = pW1 + 256 * 256;   dst = ws + 294912; KT = 4; }
  else if (b < 192) { b -= 160; src = pW2;               dst = ws + 327680; KT = 8; }
  else              { b -= 192; src = pW3;               dst = ws + 393216; KT = 8; }
  int t = b * 256 + (int)threadIdx.x;
  if (t >= 16 * KT * 64) return;
  int l  = t & 63;
  int kt = (t >> 6) % KT;
  int nt = t / (64 * KT);
  int n  = nt * 16 + (l & 15);
  int k0 = kt * 32 + (l >> 4) * 8;
  unsigned int o[4];
#pragma unroll
  for (int p = 0; p < 4; ++p) {
    float a = src[(size_t)(k0 + 2 * p) * 256 + n];
    float c = src[(size_t)(k0 + 2 * p + 1) * 256 + n];
    if (src2) {
      a += src2[(size_t)(k0 + 2 * p) * 256 + n];
      c += src2[(size_t)(k0 + 2 * p + 1) * 256 + n];
    }
    o[p] = pk2(a, c);
  }
  *(uint4*)(dst + (size_t)t * 8) = make_uint4(o[0], o[1], o[2], o[3]);
}

// ---------------------------------------------------------------------------
// K1 body: one (gp, s) tile with 256 threads (4 waves). xl = 32*264 shorts.
// cq layout (qm region): uint idx (b*256+s)*128 + k = pk2(col k, col k+128).
// cp layout (plv region): ull idx (b*256+s)*64 + w*16+lm.
// ---------------------------------------------------------------------------
template<bool FUSED>
__device__ __forceinline__ void k1_body(
    int gp, int s, int tid, unsigned short* xl,
    const float* __restrict__ enc, const unsigned short* __restrict__ wq,
    const unsigned short* __restrict__ wp, const float* __restrict__ qb1,
    unsigned int* __restrict__ cq, unsigned short* __restrict__ cp) {
  {
    int row = tid >> 3, c0 = (tid & 7) * 32;
    const float* sp = enc + (((size_t)(gp * 32 + row) * 256 + s) * 256 + c0);
#pragma unroll
    for (int q = 0; q < 4; ++q) {
      float4 a = *(const float4*)(sp + q * 8);
      float4 b = *(const float4*)(sp + q * 8 + 4);
      *(uint4*)(&xl[row * 264 + SWC(row, c0 + q * 8)]) =
          make_uint4(pk2(a.x, a.y), pk2(a.z, a.w), pk2(b.x, b.y), pk2(b.z, b.w));
    }
  }
  __syncthreads();
  const int w = tid >> 6, l = tid & 63, lm = l & 15, lg = l >> 4;
  const int rr = lg * 4;
  const int nt[4] = {2 * w, 2 * w + 1, 2 * w + 8, 2 * w + 9};
  facc4 aq[2][4], ap[2][4];
#pragma unroll
  for (int j = 0; j < 4; ++j) {
    float bv = qb1[nt[j] * 16 + lm];
    aq[0][j] = (facc4){bv, bv, bv, bv}; aq[1][j] = aq[0][j];
    ap[0][j] = (facc4){0.f, 0.f, 0.f, 0.f}; ap[1][j] = ap[0][j];
  }
#pragma unroll
  for (int kt = 0; kt < 8; ++kt) {
    bfrag8 bq[4], bp[4];
#pragma unroll
    for (int j = 0; j < 4; ++j) {
      bq[j] = *(const bfrag8*)(wq + ((size_t)(nt[j] * 8 + kt) * 64 + l) * 8);
      bp[j] = *(const bfrag8*)(wp + ((size_t)(nt[j] * 8 + kt) * 64 + l) * 8);
    }
#pragma unroll
    for (int rt = 0; rt < 2; ++rt) {
      bfrag8 x = *(const bfrag8*)(&xl[(rt * 16 + lm) * 264 + SWC(lm, kt * 32 + lg * 8)]);
#pragma unroll
      for (int j = 0; j < 4; ++j) {
        aq[rt][j] = mfma_bf16(x, bq[j], aq[rt][j]);
        ap[rt][j] = mfma_bf16(x, bp[j], ap[rt][j]);
      }
    }
  }
#pragma unroll
  for (int rt = 0; rt < 2; ++rt) {
#pragma unroll
    for (int i = 0; i < 4; ++i) {
      int b = gp * 32 + rt * 16 + rr + i;
      size_t rb = ((size_t)b * 256 + s) * 128;     // uint row base in qm region
      unsigned int v0 = pk2(aq[rt][0][i], aq[rt][2][i]);   // cols 32w+lm / +128
      unsigned int v1 = pk2(aq[rt][1][i], aq[rt][3][i]);   // cols 32w+16+lm / +128
      ull vcp = (ull)pk2(ap[rt][0][i], ap[rt][1][i]) |
                ((ull)pk2(ap[rt][2][i], ap[rt][3][i]) << 32);
      size_t cpx = ((size_t)b * 256 + s) * 64 + w * 16 + lm;
      if (FUSED) {
        __hip_atomic_store(cq + rb + 32 * w + lm,      v0, __ATOMIC_RELAXED, SCOPE_AGENT);
        __hip_atomic_store(cq + rb + 32 * w + 16 + lm, v1, __ATOMIC_RELAXED, SCOPE_AGENT);
        __hip_atomic_store((ull*)cp + cpx, vcp, __ATOMIC_RELAXED, SCOPE_AGENT);
      } else {
        cq[rb + 32 * w + lm]      = v0;
        cq[rb + 32 * w + 16 + lm] = v1;
        ((ull*)cp)[cpx] = vcp;
      }
    }
  }
}

// ---------------------------------------------------------------------------
// K2 body: sequential scan, 512 threads, 8 waves x 2 nt {w, w+8}.
// Per-group z watermark: each wave release-adds 1 to zdone[g] per 8-step chunk.
// ---------------------------------------------------------------------------
template<bool FUSED>
__device__ __forceinline__ void k2_body(
    int g, int tid, unsigned short* zl, unsigned short* h1, unsigned short* h2,
    const float* __restrict__ prevz, const float* __restrict__ eps,
    const unsigned short* __restrict__ wU, const unsigned short* __restrict__ wW2,
    const unsigned short* __restrict__ wW3,
    const float* __restrict__ qb2, const float* __restrict__ qb3,
    const unsigned int* __restrict__ cq,
    float* __restrict__ z_o, float* __restrict__ qm_o, float* __restrict__ qlv_o,
    int* cqflag, int* zdone) {
  const int w = tid >> 6, l = tid & 63, lm = l & 15, lg = l >> 4;
  const int rr = lg * 4;
  const int c = 16 * w + lm;
  const int cc[2] = {c, 128 + c};

  bfrag8 u[2][4], w2[2][8], w3[2][8];
#pragma unroll
  for (int j = 0; j < 2; ++j) {
    const int nt = w + 8 * j;
#pragma unroll
    for (int kt = 0; kt < 4; ++kt)
      u[j][kt] = load_pin(wU + ((size_t)(nt * 4 + kt) * 64 + l) * 8);
#pragma unroll
    for (int kt = 0; kt < 8; ++kt) {
      w2[j][kt] = load_pin(wW2 + ((size_t)(nt * 8 + kt) * 64 + l) * 8);
      w3[j][kt] = load_pin(wW3 + ((size_t)(nt * 8 + kt) * 64 + l) * 8);
    }
  }
  const float b2[2] = {qb2[c], qb2[128 + c]};
  const float b3[2] = {qb3[c], qb3[128 + c]};
  {
    int row = tid >> 5, q0 = (tid & 31) * 4;
    float4 v = *(const float4*)(prevz + (size_t)(g * 16 + row) * 128 + q0);
    *(uint2*)(&zl[row * 136 + SWC(row, q0)]) = make_uint2(pk2(v.x, v.y), pk2(v.z, v.w));
  }
  if (FUSED) {
    if (tid == 0)
      while (__hip_atomic_load(&cqflag[0], __ATOMIC_ACQUIRE, SCOPE_AGENT) < 32)
        __builtin_amdgcn_s_sleep(2);
    wg_barrier();
  }
  size_t rix[4];
#pragma unroll
  for (int i = 0; i < 4; ++i)
    rix[i] = ((size_t)(g * 16 + rr + i) * 256) * 128 + c;   // + s*128 per step
  unsigned int cb[4];
#pragma unroll
  for (int i = 0; i < 4; ++i) cb[i] = cq[rix[i]];
  float ep[4];
#pragma unroll
  for (int i = 0; i < 4; ++i)
    ep[i] = eps[((size_t)(g * 16 + rr + i) * 256) * 128 + c];
  __syncthreads();

  for (int sb = 0; sb < 32; ++sb) {
    if (FUSED) {
      // publish this wave's z through step 8*sb-1 into group watermark
      if (sb > 0 && l == 0)
        __hip_atomic_fetch_add(&zdone[g], 1, __ATOMIC_RELEASE, SCOPE_AGENT);
      // wait for cq rows needed by this chunk's prefetches (sn in [8sb+1, 8sb+8])
      if (tid == 0) {
        int hi = sb * 8 + 8; if (hi > 255) hi = 255;
        for (int q = sb * 8 + 1; q <= hi; ++q)
          while (__hip_atomic_load(&cqflag[q], __ATOMIC_ACQUIRE, SCOPE_AGENT) < 32)
            __builtin_amdgcn_s_sleep(2);
      }
      wg_barrier();
    }
#pragma unroll 1
    for (int si = 0; si < 8; ++si) {
      const int s = sb * 8 + si;
      facc4 a[2];
#pragma unroll
      for (int i = 0; i < 4; ++i) {
        a[0][i] = bf2f(cb[i] & 0xffffu);
        a[1][i] = bf2f(cb[i] >> 16);
      }
      const int sn = (s + 1 < 256) ? s + 1 : s;
      unsigned int nbv[4];
#pragma unroll
      for (int i = 0; i < 4; ++i) nbv[i] = cq[rix[i] + (size_t)sn * 128];
      float epn[4];
#pragma unroll
      for (int i = 0; i < 4; ++i)
        epn[i] = eps[((size_t)(g * 16 + rr + i) * 256 + sn) * 128 + c];
      // ---- layer 1 ----
#pragma unroll
      for (int kt = 0; kt < 4; ++kt) {
        bfrag8 zf = *(const bfrag8*)(&zl[lm * 136 + SWC(lm, kt * 32 + lg * 8)]);
        a[0] = mfma_bf16(zf, u[0][kt], a[0]);
        a[1] = mfma_bf16(zf, u[1][kt], a[1]);
      }
#pragma unroll
      for (int j = 0; j < 2; ++j)
#pragma unroll
        for (int i = 0; i < 4; ++i)
          h1[(rr + i) * 264 + SWC(rr + i, cc[j])] = f2bf(fmaxf(a[j][i], 0.f));
      wg_barrier();
      // ---- layer 2 ----
      facc4 cv[2] = {(facc4){b2[0], b2[0], b2[0], b2[0]},
                     (facc4){b2[1], b2[1], b2[1], b2[1]}};
#pragma unroll
      for (int kt = 0; kt < 8; ++kt) {
        bfrag8 hf = *(const bfrag8*)(&h1[lm * 264 + SWC(lm, kt * 32 + lg * 8)]);
        cv[0] = mfma_bf16(hf, w2[0][kt], cv[0]);
        cv[1] = mfma_bf16(hf, w2[1][kt], cv[1]);
      }
#pragma unroll
      for (int j = 0; j < 2; ++j)
#pragma unroll
        for (int i = 0; i < 4; ++i)
          h2[(rr + i) * 264 + SWC(rr + i, cc[j])] = f2bf(fmaxf(cv[j][i], 0.f));
      wg_barrier();
      // ---- layer 3 + reparameterization, in-lane ----
      facc4 o[2] = {(facc4){b3[0], b3[0], b3[0], b3[0]},
                    (facc4){b3[1], b3[1], b3[1], b3[1]}};
#pragma unroll
      for (int kt = 0; kt < 8; ++kt) {
        bfrag8 hf = *(const bfrag8*)(&h2[lm * 264 + SWC(lm, kt * 32 + lg * 8)]);
        o[0] = mfma_bf16(hf, w3[0][kt], o[0]);
        o[1] = mfma_bf16(hf, w3[1][kt], o[1]);
      }
#pragma unroll
      for (int i = 0; i < 4; ++i) {
        size_t ob = ((size_t)(g * 16 + rr + i) * 256 + s) * 128;
        float zq = o[0][i] + ep[i] * __expf(0.5f * o[1][i]);
        qm_o[ob + c]  = o[0][i];     // overwrites this row's consumed cq pair
        qlv_o[ob + c] = o[1][i];
        if (FUSED)
          __hip_atomic_store(&z_o[ob + c], zq, __ATOMIC_RELAXED, SCOPE_AGENT);
        else
          z_o[ob + c] = zq;
        zl[(rr + i) * 136 + SWC(rr + i, c)] = f2bf(zq);
      }
      wg_barrier();
#pragma unroll
      for (int i = 0; i < 4; ++i) { cb[i] = nbv[i]; ep[i] = epn[i]; }
    }
  }
  if (FUSED) {
    asm volatile("s_waitcnt vmcnt(0)" ::: "memory");
    if (l == 0)
      __hip_atomic_fetch_add(&zdone[g], 1, __ATOMIC_RELEASE, SCOPE_AGENT);  // z<=255
  }
}

// ---------------------------------------------------------------------------
// K3 body: prior MLP, one (gp64, s), 256 threads. Waits on zdone[4gp..4gp+3].
// ---------------------------------------------------------------------------
template<bool FUSED>
__device__ __forceinline__ void k3_body(
    int gp, int s, int tid, unsigned short* zl, unsigned short* hb,
    const float* __restrict__ prevz, const float* __restrict__ z_in,
    const unsigned short* __restrict__ cp,
    const unsigned short* __restrict__ wU, const unsigned short* __restrict__ w2p,
    const unsigned short* __restrict__ w3p,
    const float* __restrict__ pb1, const float* __restrict__ pb2,
    const float* __restrict__ pb3,
    float* __restrict__ pm_o, float* __restrict__ plv_o,
    int* cqflag, int* zdone) {
  if (FUSED) {
    if (tid == 0) {
      while (__hip_atomic_load(&cqflag[s], __ATOMIC_ACQUIRE, SCOPE_AGENT) < 32)
        __builtin_amdgcn_s_sleep(32);
      int need = 8 * ((s + 7) >> 3);   // per-group watermark for z through s-1
      if (need) {
#pragma unroll
        for (int j = 0; j < 4; ++j)
          while (__hip_atomic_load(&zdone[4 * gp + j], __ATOMIC_ACQUIRE, SCOPE_AGENT) < need)
            __builtin_amdgcn_s_sleep(32);
      }
    }
    __syncthreads();
  }
  const int w = tid >> 6, l = tid & 63, lm = l & 15, lg = l >> 4;
  const int rr = lg * 4;
  const int nt[4] = {2 * w, 2 * w + 1, 2 * w + 8, 2 * w + 9};
  const int c0 = 32 * w + lm, c1 = c0 + 16;
  const int cc[4] = {c0, c1, 128 + c0, 128 + c1};
  {
    int row = tid >> 2, q0 = (tid & 3) * 32;
    const float* sp = (s == 0) ? (prevz + (size_t)(gp * 64 + row) * 128 + q0)
                               : (z_in + ((size_t)(gp * 64 + row) * 256 + (s - 1)) * 128 + q0);
#pragma unroll
    for (int q = 0; q < 4; ++q) {
      float4 a = *(const float4*)(sp + q * 8);
      float4 b = *(const float4*)(sp + q * 8 + 4);
      *(uint4*)(&zl[row * 136 + SWC(row, q0 + q * 8)]) =
          make_uint4(pk2(a.x, a.y), pk2(a.z, a.w), pk2(b.x, b.y), pk2(b.z, b.w));
    }
  }
  const float pb[4] = {pb1[nt[0] * 16 + lm], pb1[nt[1] * 16 + lm],
                       pb1[nt[2] * 16 + lm], pb1[nt[3] * 16 + lm]};
  facc4 acc[4][4];
#pragma unroll
  for (int rt = 0; rt < 4; ++rt)
#pragma unroll
    for (int i = 0; i < 4; ++i) {
      int b = gp * 64 + rt * 16 + rr + i;
      ull v = ((const ull*)cp)[((size_t)b * 256 + s) * 64 + w * 16 + lm];
      unsigned int vx = (unsigned int)v, vy = (unsigned int)(v >> 32);
      acc[rt][0][i] = pb[0] + bf2f(vx & 0xffffu);
      acc[rt][1][i] = pb[1] + bf2f(vx >> 16);
      acc[rt][2][i] = pb[2] + bf2f(vy & 0xffffu);
      acc[rt][3][i] = pb[3] + bf2f(vy >> 16);
    }
  __syncthreads();
  // ---- layer 1: + z @ Up ----
#pragma unroll
  for (int kt = 0; kt < 4; ++kt) {
    bfrag8 b0 = *(const bfrag8*)(wU + ((size_t)(nt[0] * 4 + kt) * 64 + l) * 8);
    bfrag8 b1 = *(const bfrag8*)(wU + ((size_t)(nt[1] * 4 + kt) * 64 + l) * 8);
    bfrag8 b2f = *(const bfrag8*)(wU + ((size_t)(nt[2] * 4 + kt) * 64 + l) * 8);
    bfrag8 b3f = *(const bfrag8*)(wU + ((size_t)(nt[3] * 4 + kt) * 64 + l) * 8);
#pragma unroll
    for (int rt = 0; rt < 4; ++rt) {
      bfrag8 zf = *(const bfrag8*)(&zl[(rt * 16 + lm) * 136 + SWC(lm, kt * 32 + lg * 8)]);
      acc[rt][0] = mfma_bf16(zf, b0, acc[rt][0]);
      acc[rt][1] = mfma_bf16(zf, b1, acc[rt][1]);
      acc[rt][2] = mfma_bf16(zf, b2f, acc[rt][2]);
      acc[rt][3] = mfma_bf16(zf, b3f, acc[rt][3]);
    }
  }
#pragma unroll
  for (int rt = 0; rt < 4; ++rt)
#pragma unroll
    for (int j = 0; j < 4; ++j)
#pragma unroll
      for (int i = 0; i < 4; ++i) {
        int r = rt * 16 + rr + i;
        hb[r * 264 + SWC(r, cc[j])] = f2bf(fmaxf(acc[rt][j][i], 0.f));
      }
  __syncthreads();
  // ---- layer 2 ----
  facc4 a2[4][4];
#pragma unroll
  for (int rt = 0; rt < 4; ++rt)
#pragma unroll
    for (int j = 0; j < 4; ++j) a2[rt][j] = (facc4){pb2[nt[j] * 16 + lm], pb2[nt[j] * 16 + lm],
                                                    pb2[nt[j] * 16 + lm], pb2[nt[j] * 16 + lm]};
#pragma unroll
  for (int kt = 0; kt < 8; ++kt) {
    bfrag8 b0 = *(const bfrag8*)(w2p + ((size_t)(nt[0] * 8 + kt) * 64 + l) * 8);
    bfrag8 b1 = *(const bfrag8*)(w2p + ((size_t)(nt[1] * 8 + kt) * 64 + l) * 8);
    bfrag8 b2f = *(const bfrag8*)(w2p + ((size_t)(nt[2] * 8 + kt) * 64 + l) * 8);
    bfrag8 b3f = *(const bfrag8*)(w2p + ((size_t)(nt[3] * 8 + kt) * 64 + l) * 8);
#pragma unroll
    for (int rt = 0; rt < 4; ++rt) {
      bfrag8 hf = *(const bfrag8*)(&hb[(rt * 16 + lm) * 264 + SWC(lm, kt * 32 + lg * 8)]);
      a2[rt][0] = mfma_bf16(hf, b0, a2[rt][0]);
      a2[rt][1] = mfma_bf16(hf, b1, a2[rt][1]);
      a2[rt][2] = mfma_bf16(hf, b2f, a2[rt][2]);
      a2[rt][3] = mfma_bf16(hf, b3f, a2[rt][3]);
    }
  }
  __syncthreads();
#pragma unroll
  for (int rt = 0; rt < 4; ++rt)
#pragma unroll
    for (int j = 0; j < 4; ++j)
#pragma unroll
      for (int i = 0; i < 4; ++i) {
        int r = rt * 16 + rr + i;
        hb[r * 264 + SWC(r, cc[j])] = f2bf(fmaxf(a2[rt][j][i], 0.f));
      }
  __syncthreads();
  // ---- layer 3 ----
  facc4 a3[4][4];
#pragma unroll
  for (int rt = 0; rt < 4; ++rt)
#pragma unroll
    for (int j = 0; j < 4; ++j) a3[rt][j] = (facc4){pb3[nt[j] * 16 + lm], pb3[nt[j] * 16 + lm],
                                                    pb3[nt[j] * 16 + lm], pb3[nt[j] * 16 + lm]};
#pragma unroll
  for (int kt = 0; kt < 8; ++kt) {
    bfrag8 b0 = *(const bfrag8*)(w3p + ((size_t)(nt[0] * 8 + kt) * 64 + l) * 8);
    bfrag8 b1 = *(const bfrag8*)(w3p + ((size_t)(nt[1] * 8 + kt) * 64 + l) * 8);
    bfrag8 b2f = *(const bfrag8*)(w3p + ((size_t)(nt[2] * 8 + kt) * 64 + l) * 8);
    bfrag8 b3f = *(const bfrag8*)(w3p + ((size_t)(nt[3] * 8 + kt) * 64 + l) * 8);
#pragma unroll
    for (int rt = 0; rt < 4; ++rt) {
      bfrag8 hf = *(const bfrag8*)(&hb[(rt * 16 + lm) * 264 + SWC(lm, kt * 32 + lg * 8)]);
      a3[rt][0] = mfma_bf16(hf, b0, a3[rt][0]);
      a3[rt][1] = mfma_bf16(hf, b1, a3[rt][1]);
      a3[rt][2] = mfma_bf16(hf, b2f, a3[rt][2]);
      a3[rt][3] = mfma_bf16(hf, b3f, a3[rt][3]);
    }
  }
#pragma unroll
  for (int rt = 0; rt < 4; ++rt)
#pragma unroll
    for (int i = 0; i < 4; ++i) {
      size_t base = ((size_t)(gp * 64 + rt * 16 + rr + i) * 256 + s) * 128;
      pm_o[base + c0]  = a3[rt][0][i];
      pm_o[base + c1]  = a3[rt][1][i];
      plv_o[base + c0] = a3[rt][2][i];
      plv_o[base + c1] = a3[rt][3][i];
    }
}

// ---------------------------------------------------------------------------
// Fused mega-kernel. Block order: k2 (64, FIRST -> exclusive CUs) | k1 (4096,
// s-major, 2 s/block) | k3 (4096, s-major). 512 threads. 84 KB dynamic LDS
// forces 1 block/CU (2x84 KB > 160 KB) so k2 never shares a CU.
// ---------------------------------------------------------------------------
__global__ __launch_bounds__(512, 2) void mega(
    const float* __restrict__ enc, const float* __restrict__ prevz,
    const float* __restrict__ eps,
    const unsigned short* __restrict__ Wqe, const unsigned short* __restrict__ Uq,
    const unsigned short* __restrict__ W2q, const unsigned short* __restrict__ W3q,
    const unsigned short* __restrict__ W1ph, const unsigned short* __restrict__ Up,
    const unsigned short* __restrict__ W2p, const unsigned short* __restrict__ W3p,
    const float* __restrict__ qb1, const float* __restrict__ qb2,
    const float* __restrict__ qb3, const float* __restrict__ pb1,
    const float* __restrict__ pb2, const float* __restrict__ pb3,
    unsigned int* cq, unsigned short* cp,
    float* z_o, float* qm_o, float* qlv_o, float* pm_o, float* plv_o,
    int* cqflag, int* zdone) {
  extern __shared__ __align__(16) char smem[];   // 86016 B at launch
  const int bid = blockIdx.x;
  const int tid = threadIdx.x;
  if (bid < 64) {
    // ---- k2: dispatched first, 1 block/CU -> exclusive CU ----
    const int g = bid;
    unsigned short* zl = (unsigned short*)smem;
    unsigned short* h1 = zl + 16 * 136;
    unsigned short* h2 = h1 + 16 * 264;
    k2_body<true>(g, tid, zl, h1, h2, prevz, eps, Uq, W2q, W3q, qb2, qb3, cq,
                  z_o, qm_o, qlv_o, cqflag, zdone);
  } else if (bid < 4160) {
    // ---- k1: two s-tiles per block (one per 256-thread half) ----
    const int kb = bid - 64;
    const int spair = kb >> 5, gp = kb & 31;
    const int h = tid >> 8, t = tid & 255;
    const int s = 2 * spair + h;
    unsigned short* xl = (unsigned short*)smem + h * (32 * 264);
    k1_body<true>(gp, s, t, xl, enc, Wqe, W1ph, qb1, cq, cp);
    __syncthreads();   // each wave drains vmcnt before barrier -> stores visible
    if (tid == 0) {
      __hip_atomic_fetch_add(&cqflag[2 * spair],     1, __ATOMIC_RELEASE, SCOPE_AGENT);
      __hip_atomic_fetch_add(&cqflag[2 * spair + 1], 1, __ATOMIC_RELEASE, SCOPE_AGENT);
    }
  } else {
    // ---- k3 ----
    if (tid >= 256) return;
    const int b2 = bid - 4160;
    const int s = b2 >> 4, gp = b2 & 15;
    unsigned short* zl = (unsigned short*)smem;
    unsigned short* hb = zl + 64 * 136;
    k3_body<true>(gp, s, tid, zl, hb, prevz, z_o, cp, Up, W2p, W3p,
                  pb1, pb2, pb3, pm_o, plv_o, cqflag, zdone);
  }
}

// ---------------------------------------------------------------------------
// Fallback sequential kernels (used if ws too small or attribute set fails).
// ---------------------------------------------------------------------------
__global__ __launch_bounds__(256, 2) void k1_pre(
    const float* __restrict__ enc, const unsigned short* __restrict__ wq,
    const unsigned short* __restrict__ wp, const float* __restrict__ qb1,
    unsigned int* __restrict__ cq, unsigned short* __restrict__ cp) {
  __shared__ unsigned short xl[32 * 264];
  k1_body<false>(blockIdx.x >> 8, blockIdx.x & 255, threadIdx.x, xl,
                 enc, wq, wp, qb1, cq, cp);
}
__global__ __launch_bounds__(512, 2) void k2_scan(
    const float* __restrict__ prevz, const float* __restrict__ eps,
    const unsigned short* __restrict__ wU, const unsigned short* __restrict__ wW2,
    const unsigned short* __restrict__ wW3,
    const float* __restrict__ qb2, const float* __restrict__ qb3,
    const unsigned int* __restrict__ cq,
    float* __restrict__ z_o, float* __restrict__ qm_o, float* __restrict__ qlv_o) {
  __shared__ unsigned short zl[16 * 136];
  __shared__ unsigned short h1[16 * 264];
  __shared__ unsigned short h2[16 * 264];
  k2_body<false>(blockIdx.x, threadIdx.x, zl, h1, h2, prevz, eps, wU, wW2, wW3,
                 qb2, qb3, cq, z_o, qm_o, qlv_o, nullptr, nullptr);
}
__global__ __launch_bounds__(256, 2) void k3_prior(
    const float* __restrict__ prevz, const float* __restrict__ z_in,
    const unsigned short* __restrict__ cp,
    const unsigned short* __restrict__ wU, const unsigned short* __restrict__ w2p,
    const unsigned short* __restrict__ w3p,
    const float* __restrict__ pb1, const float* __restrict__ pb2,
    const float* __restrict__ pb3,
    float* __restrict__ pm_o, float* __restrict__ plv_o) {
  __shared__ unsigned short zl[64 * 136];
  __shared__ unsigned short hb[64 * 264];
  k3_body<false>(blockIdx.x >> 8, blockIdx.x & 255, threadIdx.x, zl, hb,
                 prevz, z_in, cp, wU, w2p, w3p, pb1, pb2, pb3, pm_o, plv_o,
                 nullptr, nullptr);
}

// ---------------------------------------------------------------------------
extern "C" void kernel_launch(void* const* d_in, const int* in_sizes, int n_in,
                              void* d_out, int out_size, void* d_ws, size_t ws_size,
                              hipStream_t stream) {
  const float* enc   = (const float*)d_in[0];
  const float* prevz = (const float*)d_in[1];
  const float* eps   = (const float*)d_in[2];
  const float* pW1 = (const float*)d_in[3];
  const float* pb1 = (const float*)d_in[4];
  const float* pW2 = (const float*)d_in[5];
  const float* pb2 = (const float*)d_in[6];
  const float* pW3 = (const float*)d_in[7];
  const float* pb3 = (const float*)d_in[8];
  const float* qW1 = (const float*)d_in[9];
  const float* qb1 = (const float*)d_in[10];
  const float* qW2 = (const float*)d_in[11];
  const float* qb2 = (const float*)d_in[12];
  const float* qW3 = (const float*)d_in[13];
  const float* qb3 = (const float*)d_in[14];

  float* out = (float*)d_out;
  const size_t O = (size_t)1024 * 256 * 128;
  float* z_o   = out;
  float* pm_o  = out + O;
  float* plv_o = out + 2 * O;
  float* qm_o  = out + 3 * O;
  float* qlv_o = out + 4 * O;
  unsigned int*   cq = (unsigned int*)qm_o;     // row-aligned Cq pairs (k2 input;
                                                // k2 itself overwrites with qm)
  unsigned short* cp = (unsigned short*)plv_o;  // row-aligned Cp (k3 input)

  unsigned short* ws = (unsigned short*)d_ws;
  unsigned short* Wqe  = ws;             // 65536
  unsigned short* Uq   = ws + 65536;     // 32768
  unsigned short* W2q  = ws + 98304;     // 65536
  unsigned short* W3q  = ws + 163840;    // 65536
  unsigned short* W1ph = ws + 229376;    // 65536
  unsigned short* Up   = ws + 294912;    // 32768
  unsigned short* W2p  = ws + 327680;    // 65536
  unsigned short* W3p  = ws + 393216;    // 65536 (weights end: 458752 shorts)

  const size_t FLAGS_OFF = 458752u * 2u;          // bytes
  int* cqflag = (int*)((char*)d_ws + FLAGS_OFF);  // 256 ints
  int* zdone  = cqflag + 256;                     // 64 ints (per k2 group)
  const int MEGA_LDS = 86016;                     // 84 KB -> 1 block/CU
  bool fused = ws_size >= FLAGS_OFF + 320 * sizeof(int);
  if (fused &&
      hipFuncSetAttribute((const void*)mega,
                          hipFuncAttributeMaxDynamicSharedMemorySize,
                          MEGA_LDS) != hipSuccess)
    fused = false;

  pack_all<<<224, 256, 0, stream>>>(qW1, qW2, qW3, pW1, pW2, pW3, ws);
  if (fused) {
    hipMemsetAsync(cqflag, 0, 320 * sizeof(int), stream);
    mega<<<8256, 512, MEGA_LDS, stream>>>(enc, prevz, eps,
                                          Wqe, Uq, W2q, W3q, W1ph, Up, W2p, W3p,
                                          qb1, qb2, qb3, pb1, pb2, pb3,
                                          cq, cp, z_o, qm_o, qlv_o, pm_o, plv_o,
                                          cqflag, zdone);
  } else {
    k1_pre<<<8192, 256, 0, stream>>>(enc, Wqe, W1ph, qb1, cq, cp);
    k2_scan<<<64, 512, 0, stream>>>(prevz, eps, Uq, W2q, W3q, qb2, qb3, cq,
                                    z_o, qm_o, qlv_o);
    k3_prior<<<4096, 256, 0, stream>>>(prevz, z_o, cp, Up, W2p, W3p,
                                       pb1, pb2, pb3, pm_o, plv_o);
  }
}

// Round 10
// 1297.711 us; speedup vs baseline: 1.7649x; 1.3291x over previous
//
#include <hip/hip_runtime.h>

// ---------------------------------------------------------------------------
// ConditionalVariationalModule: B=1024, S=256, INPUT=256, LATENT=128, HIDDEN=256
// Pipeline:
//   pack_all : weights -> B-fragment order (d_ws)
//   k1_pre   : Cq (row-aligned bf16 pairs, qm region) + Cp (plv region), plain
//   mega2    : k2 scan (64 blocks, FIRST, CU-exclusive via 84 KB dyn LDS)
//              + k3 prior (4096 blocks) polling per-group z watermarks with
//              RELAXED loads only; z read via uncached agent atomic loads.
//              -> zero acquire operations: no L2-invalidation storms.
// Outputs (fp32): z | pm | plv | qm | qlv, each [B,S,128].
// ---------------------------------------------------------------------------

typedef __attribute__((ext_vector_type(8))) short bfrag8;   // 8 bf16 = 4 VGPR
typedef __attribute__((ext_vector_type(4))) float facc4;    // MFMA accum
typedef __attribute__((ext_vector_type(4))) unsigned int u32x4;
typedef unsigned long long ull;

#define SCOPE_AGENT __HIP_MEMORY_SCOPE_AGENT

__device__ __forceinline__ unsigned short f2bf(float x) {
  unsigned int u = __float_as_uint(x);
  u = (u + 0x7fffu + ((u >> 16) & 1u)) >> 16;   // RNE
  return (unsigned short)u;
}
__device__ __forceinline__ unsigned int pk2(float a, float b) {
  return (unsigned int)f2bf(a) | ((unsigned int)f2bf(b) << 16);
}
__device__ __forceinline__ float bf2f(unsigned int lo) {
  return __uint_as_float(lo << 16);
}
__device__ __forceinline__ facc4 mfma_bf16(bfrag8 a, bfrag8 b, facc4 c) {
  return __builtin_amdgcn_mfma_f32_16x16x32_bf16(a, b, c, 0, 0, 0);
}
__device__ __forceinline__ bfrag8 load_pin(const unsigned short* p) {
  u32x4 v = *(const u32x4*)p;
  asm volatile("" : "+v"(v));
  return __builtin_bit_cast(bfrag8, v);
}
__device__ __forceinline__ void wg_barrier() {
  asm volatile("s_waitcnt lgkmcnt(0)" ::: "memory");
  __builtin_amdgcn_sched_barrier(0);
  __builtin_amdgcn_s_barrier();
  __builtin_amdgcn_sched_barrier(0);
}
#define SWC(r, c) ((c) ^ (((r) & 8) << 1))

// ---------------------------------------------------------------------------
// Pack all 8 weight matrices into B-fragment order.
// ---------------------------------------------------------------------------
__global__ void pack_all(const float* __restrict__ qW1, const float* __restrict__ qW2,
                         const float* __restrict__ qW3, const float* __restrict__ pW1,
                         const float* __restrict__ pW2, const float* __restrict__ pW3,
                         unsigned short* __restrict__ ws) {
  int b = blockIdx.x;
  const float* src; const float* src2 = nullptr; unsigned short* dst; int KT;
  if (b < 32)       { src = qW1; src2 = qW1 + 384 * 256; dst = ws;          KT = 8; }
  else if (b < 48)  { b -= 32;  src = qW1 + 256 * 256;   dst = ws + 65536;  KT = 4; }
  else if (b < 80)  { b -= 48;  src = qW2;               dst = ws + 98304;  KT = 8; }
  else if (b < 112) { b -= 80;  src = qW3;               dst = ws + 163840; KT = 8; }
  else if (b < 144) { b -= 112; src = pW1;               dst = ws + 229376; KT = 8; }
  else if (b < 160) { b -= 144; src = pW1 + 256 * 256;   dst = ws + 294912; KT = 4; }
  else if (b < 192) { b -= 160; src = pW2;               dst = ws + 327680; KT = 8; }
  else              { b -= 192; src = pW3;               dst = ws + 393216; KT = 8; }
  int t = b * 256 + (int)threadIdx.x;
  if (t >= 16 * KT * 64) return;
  int l  = t & 63;
  int kt = (t >> 6) % KT;
  int nt = t / (64 * KT);
  int n  = nt * 16 + (l & 15);
  int k0 = kt * 32 + (l >> 4) * 8;
  unsigned int o[4];
#pragma unroll
  for (int p = 0; p < 4; ++p) {
    float a = src[(size_t)(k0 + 2 * p) * 256 + n];
    float c = src[(size_t)(k0 + 2 * p + 1) * 256 + n];
    if (src2) {
      a += src2[(size_t)(k0 + 2 * p) * 256 + n];
      c += src2[(size_t)(k0 + 2 * p + 1) * 256 + n];
    }
    o[p] = pk2(a, c);
  }
  *(uint4*)(dst + (size_t)t * 8) = make_uint4(o[0], o[1], o[2], o[3]);
}

// ---------------------------------------------------------------------------
// K1: one (gp, s) tile per block, 256 threads (4 waves). Plain stores.
// cq layout (qm region): uint idx (b*256+s)*128 + k = pk2(col k, col k+128).
// cp layout (plv region): ull idx (b*256+s)*64 + w*16+lm.
// ---------------------------------------------------------------------------
__global__ __launch_bounds__(256, 2) void k1_pre(
    const float* __restrict__ enc, const unsigned short* __restrict__ wq,
    const unsigned short* __restrict__ wp, const float* __restrict__ qb1,
    unsigned int* __restrict__ cq, unsigned short* __restrict__ cp) {
  __shared__ unsigned short xl[32 * 264];
  const int gp = blockIdx.x >> 8, s = blockIdx.x & 255;
  const int tid = threadIdx.x;
  {
    int row = tid >> 3, c0 = (tid & 7) * 32;
    const float* sp = enc + (((size_t)(gp * 32 + row) * 256 + s) * 256 + c0);
#pragma unroll
    for (int q = 0; q < 4; ++q) {
      float4 a = *(const float4*)(sp + q * 8);
      float4 b = *(const float4*)(sp + q * 8 + 4);
      *(uint4*)(&xl[row * 264 + SWC(row, c0 + q * 8)]) =
          make_uint4(pk2(a.x, a.y), pk2(a.z, a.w), pk2(b.x, b.y), pk2(b.z, b.w));
    }
  }
  __syncthreads();
  const int w = tid >> 6, l = tid & 63, lm = l & 15, lg = l >> 4;
  const int rr = lg * 4;
  const int nt[4] = {2 * w, 2 * w + 1, 2 * w + 8, 2 * w + 9};
  facc4 aq[2][4], ap[2][4];
#pragma unroll
  for (int j = 0; j < 4; ++j) {
    float bv = qb1[nt[j] * 16 + lm];
    aq[0][j] = (facc4){bv, bv, bv, bv}; aq[1][j] = aq[0][j];
    ap[0][j] = (facc4){0.f, 0.f, 0.f, 0.f}; ap[1][j] = ap[0][j];
  }
#pragma unroll
  for (int kt = 0; kt < 8; ++kt) {
    bfrag8 bq[4], bp[4];
#pragma unroll
    for (int j = 0; j < 4; ++j) {
      bq[j] = *(const bfrag8*)(wq + ((size_t)(nt[j] * 8 + kt) * 64 + l) * 8);
      bp[j] = *(const bfrag8*)(wp + ((size_t)(nt[j] * 8 + kt) * 64 + l) * 8);
    }
#pragma unroll
    for (int rt = 0; rt < 2; ++rt) {
      bfrag8 x = *(const bfrag8*)(&xl[(rt * 16 + lm) * 264 + SWC(lm, kt * 32 + lg * 8)]);
#pragma unroll
      for (int j = 0; j < 4; ++j) {
        aq[rt][j] = mfma_bf16(x, bq[j], aq[rt][j]);
        ap[rt][j] = mfma_bf16(x, bp[j], ap[rt][j]);
      }
    }
  }
#pragma unroll
  for (int rt = 0; rt < 2; ++rt) {
#pragma unroll
    for (int i = 0; i < 4; ++i) {
      int b = gp * 32 + rt * 16 + rr + i;
      size_t rb = ((size_t)b * 256 + s) * 128;
      cq[rb + 32 * w + lm]      = pk2(aq[rt][0][i], aq[rt][2][i]);
      cq[rb + 32 * w + 16 + lm] = pk2(aq[rt][1][i], aq[rt][3][i]);
      ((ull*)cp)[((size_t)b * 256 + s) * 64 + w * 16 + lm] =
          (ull)pk2(ap[rt][0][i], ap[rt][1][i]) |
          ((ull)pk2(ap[rt][2][i], ap[rt][3][i]) << 32);
    }
  }
}

// ---------------------------------------------------------------------------
// K2 body: sequential scan, 512 threads, 8 waves x 2 nt {w, w+8}.
// PUB=1: z stores uncached (agent relaxed); one release-RMW on zdone[g] per
// wave per 8-step chunk. No waits anywhere.
// ---------------------------------------------------------------------------
template<int PUB>
__device__ __forceinline__ void k2_body(
    int g, int tid, unsigned short* zl, unsigned short* h1, unsigned short* h2,
    const float* __restrict__ prevz, const float* __restrict__ eps,
    const unsigned short* __restrict__ wU, const unsigned short* __restrict__ wW2,
    const unsigned short* __restrict__ wW3,
    const float* __restrict__ qb2, const float* __restrict__ qb3,
    const unsigned int* __restrict__ cq,
    float* __restrict__ z_o, float* __restrict__ qm_o, float* __restrict__ qlv_o,
    int* zdone) {
  const int w = tid >> 6, l = tid & 63, lm = l & 15, lg = l >> 4;
  const int rr = lg * 4;
  const int c = 16 * w + lm;
  const int cc[2] = {c, 128 + c};

  bfrag8 u[2][4], w2[2][8], w3[2][8];
#pragma unroll
  for (int j = 0; j < 2; ++j) {
    const int nt = w + 8 * j;
#pragma unroll
    for (int kt = 0; kt < 4; ++kt)
      u[j][kt] = load_pin(wU + ((size_t)(nt * 4 + kt) * 64 + l) * 8);
#pragma unroll
    for (int kt = 0; kt < 8; ++kt) {
      w2[j][kt] = load_pin(wW2 + ((size_t)(nt * 8 + kt) * 64 + l) * 8);
      w3[j][kt] = load_pin(wW3 + ((size_t)(nt * 8 + kt) * 64 + l) * 8);
    }
  }
  const float b2[2] = {qb2[c], qb2[128 + c]};
  const float b3[2] = {qb3[c], qb3[128 + c]};
  {
    int row = tid >> 5, q0 = (tid & 31) * 4;
    float4 v = *(const float4*)(prevz + (size_t)(g * 16 + row) * 128 + q0);
    *(uint2*)(&zl[row * 136 + SWC(row, q0)]) = make_uint2(pk2(v.x, v.y), pk2(v.z, v.w));
  }
  size_t rix[4];
#pragma unroll
  for (int i = 0; i < 4; ++i)
    rix[i] = ((size_t)(g * 16 + rr + i) * 256) * 128 + c;   // + s*128 per step
  unsigned int cb[4];
#pragma unroll
  for (int i = 0; i < 4; ++i) cb[i] = cq[rix[i]];
  float ep[4];
#pragma unroll
  for (int i = 0; i < 4; ++i)
    ep[i] = eps[((size_t)(g * 16 + rr + i) * 256) * 128 + c];
  __syncthreads();

  for (int sb = 0; sb < 32; ++sb) {
    if (PUB && sb > 0 && l == 0)
      __hip_atomic_fetch_add(&zdone[g], 1, __ATOMIC_RELEASE, SCOPE_AGENT);
#pragma unroll 1
    for (int si = 0; si < 8; ++si) {
      const int s = sb * 8 + si;
      facc4 a[2];
#pragma unroll
      for (int i = 0; i < 4; ++i) {
        a[0][i] = bf2f(cb[i] & 0xffffu);
        a[1][i] = bf2f(cb[i] >> 16);
      }
      const int sn = (s + 1 < 256) ? s + 1 : s;
      unsigned int nbv[4];
#pragma unroll
      for (int i = 0; i < 4; ++i) nbv[i] = cq[rix[i] + (size_t)sn * 128];
      float epn[4];
#pragma unroll
      for (int i = 0; i < 4; ++i)
        epn[i] = eps[((size_t)(g * 16 + rr + i) * 256 + sn) * 128 + c];
      // ---- layer 1 ----
#pragma unroll
      for (int kt = 0; kt < 4; ++kt) {
        bfrag8 zf = *(const bfrag8*)(&zl[lm * 136 + SWC(lm, kt * 32 + lg * 8)]);
        a[0] = mfma_bf16(zf, u[0][kt], a[0]);
        a[1] = mfma_bf16(zf, u[1][kt], a[1]);
      }
#pragma unroll
      for (int j = 0; j < 2; ++j)
#pragma unroll
        for (int i = 0; i < 4; ++i)
          h1[(rr + i) * 264 + SWC(rr + i, cc[j])] = f2bf(fmaxf(a[j][i], 0.f));
      wg_barrier();
      // ---- layer 2 ----
      facc4 cv[2] = {(facc4){b2[0], b2[0], b2[0], b2[0]},
                     (facc4){b2[1], b2[1], b2[1], b2[1]}};
#pragma unroll
      for (int kt = 0; kt < 8; ++kt) {
        bfrag8 hf = *(const bfrag8*)(&h1[lm * 264 + SWC(lm, kt * 32 + lg * 8)]);
        cv[0] = mfma_bf16(hf, w2[0][kt], cv[0]);
        cv[1] = mfma_bf16(hf, w2[1][kt], cv[1]);
      }
#pragma unroll
      for (int j = 0; j < 2; ++j)
#pragma unroll
        for (int i = 0; i < 4; ++i)
          h2[(rr + i) * 264 + SWC(rr + i, cc[j])] = f2bf(fmaxf(cv[j][i], 0.f));
      wg_barrier();
      // ---- layer 3 + reparameterization, in-lane ----
      facc4 o[2] = {(facc4){b3[0], b3[0], b3[0], b3[0]},
                    (facc4){b3[1], b3[1], b3[1], b3[1]}};
#pragma unroll
      for (int kt = 0; kt < 8; ++kt) {
        bfrag8 hf = *(const bfrag8*)(&h2[lm * 264 + SWC(lm, kt * 32 + lg * 8)]);
        o[0] = mfma_bf16(hf, w3[0][kt], o[0]);
        o[1] = mfma_bf16(hf, w3[1][kt], o[1]);
      }
#pragma unroll
      for (int i = 0; i < 4; ++i) {
        size_t ob = ((size_t)(g * 16 + rr + i) * 256 + s) * 128;
        float zq = o[0][i] + ep[i] * __expf(0.5f * o[1][i]);
        qm_o[ob + c]  = o[0][i];     // overwrites this row's consumed cq pair
        qlv_o[ob + c] = o[1][i];
        if (PUB)
          __hip_atomic_store(&z_o[ob + c], zq, __ATOMIC_RELAXED, SCOPE_AGENT);
        else
          z_o[ob + c] = zq;
        zl[(rr + i) * 136 + SWC(rr + i, c)] = f2bf(zq);
      }
      wg_barrier();
#pragma unroll
      for (int i = 0; i < 4; ++i) { cb[i] = nbv[i]; ep[i] = epn[i]; }
    }
  }
  if (PUB) {
    asm volatile("s_waitcnt vmcnt(0)" ::: "memory");
    if (l == 0)
      __hip_atomic_fetch_add(&zdone[g], 1, __ATOMIC_RELEASE, SCOPE_AGENT);  // z<=255
  }
}

// ---------------------------------------------------------------------------
// K3 body: prior MLP, one (gp64, s), 256 threads.
// WAIT=1: relaxed-poll zdone[4gp..4gp+3] (no acquire, no L2 invalidation);
// read z via uncached agent-relaxed 8B atomic loads (coherence point direct).
// ---------------------------------------------------------------------------
template<int WAIT>
__device__ __forceinline__ void k3_body(
    int gp, int s, int tid, unsigned short* zl, unsigned short* hb,
    const float* __restrict__ prevz, const float* __restrict__ z_in,
    const unsigned short* __restrict__ cp,
    const unsigned short* __restrict__ wU, const unsigned short* __restrict__ w2p,
    const unsigned short* __restrict__ w3p,
    const float* __restrict__ pb1, const float* __restrict__ pb2,
    const float* __restrict__ pb3,
    float* __restrict__ pm_o, float* __restrict__ plv_o,
    int* zdone) {
  if (WAIT) {
    if (tid == 0) {
      const int need = 8 * ((s + 7) >> 3);   // z through s-1
      if (need) {
#pragma unroll
        for (int j = 0; j < 4; ++j)
          while (__hip_atomic_load(&zdone[4 * gp + j], __ATOMIC_RELAXED, SCOPE_AGENT) < need)
            __builtin_amdgcn_s_sleep(32);
      }
    }
    __syncthreads();   // full block fence; z loads below issue after this
  }
  const int w = tid >> 6, l = tid & 63, lm = l & 15, lg = l >> 4;
  const int rr = lg * 4;
  const int nt[4] = {2 * w, 2 * w + 1, 2 * w + 8, 2 * w + 9};
  const int c0 = 32 * w + lm, c1 = c0 + 16;
  const int cc[4] = {c0, c1, 128 + c0, 128 + c1};
  {
    int row = tid >> 2, q0 = (tid & 3) * 32;
    if (!WAIT || s == 0) {
      const float* sp = (s == 0) ? (prevz + (size_t)(gp * 64 + row) * 128 + q0)
                                 : (z_in + ((size_t)(gp * 64 + row) * 256 + (s - 1)) * 128 + q0);
#pragma unroll
      for (int q = 0; q < 4; ++q) {
        float4 a = *(const float4*)(sp + q * 8);
        float4 b = *(const float4*)(sp + q * 8 + 4);
        *(uint4*)(&zl[row * 136 + SWC(row, q0 + q * 8)]) =
            make_uint4(pk2(a.x, a.y), pk2(a.z, a.w), pk2(b.x, b.y), pk2(b.z, b.w));
      }
    } else {
      const ull* zp = (const ull*)(z_in + ((size_t)(gp * 64 + row) * 256 + (s - 1)) * 128 + q0);
#pragma unroll
      for (int q = 0; q < 4; ++q) {
        ull u0 = __hip_atomic_load(zp + q * 4 + 0, __ATOMIC_RELAXED, SCOPE_AGENT);
        ull u1 = __hip_atomic_load(zp + q * 4 + 1, __ATOMIC_RELAXED, SCOPE_AGENT);
        ull u2 = __hip_atomic_load(zp + q * 4 + 2, __ATOMIC_RELAXED, SCOPE_AGENT);
        ull u3 = __hip_atomic_load(zp + q * 4 + 3, __ATOMIC_RELAXED, SCOPE_AGENT);
        float f0 = __uint_as_float((unsigned)u0), f1 = __uint_as_float((unsigned)(u0 >> 32));
        float f2 = __uint_as_float((unsigned)u1), f3 = __uint_as_float((unsigned)(u1 >> 32));
        float f4 = __uint_as_float((unsigned)u2), f5 = __uint_as_float((unsigned)(u2 >> 32));
        float f6 = __uint_as_float((unsigned)u3), f7 = __uint_as_float((unsigned)(u3 >> 32));
        *(uint4*)(&zl[row * 136 + SWC(row, q0 + q * 8)]) =
            make_uint4(pk2(f0, f1), pk2(f2, f3), pk2(f4, f5), pk2(f6, f7));
      }
    }
  }
  const float pb[4] = {pb1[nt[0] * 16 + lm], pb1[nt[1] * 16 + lm],
                       pb1[nt[2] * 16 + lm], pb1[nt[3] * 16 + lm]};
  facc4 acc[4][4];
#pragma unroll
  for (int rt = 0; rt < 4; ++rt)
#pragma unroll
    for (int i = 0; i < 4; ++i) {
      int b = gp * 64 + rt * 16 + rr + i;
      ull v = ((const ull*)cp)[((size_t)b * 256 + s) * 64 + w * 16 + lm];
      unsigned int vx = (unsigned int)v, vy = (unsigned int)(v >> 32);
      acc[rt][0][i] = pb[0] + bf2f(vx & 0xffffu);
      acc[rt][1][i] = pb[1] + bf2f(vx >> 16);
      acc[rt][2][i] = pb[2] + bf2f(vy & 0xffffu);
      acc[rt][3][i] = pb[3] + bf2f(vy >> 16);
    }
  __syncthreads();
  // ---- layer 1: + z @ Up ----
#pragma unroll
  for (int kt = 0; kt < 4; ++kt) {
    bfrag8 b0 = *(const bfrag8*)(wU + ((size_t)(nt[0] * 4 + kt) * 64 + l) * 8);
    bfrag8 b1 = *(const bfrag8*)(wU + ((size_t)(nt[1] * 4 + kt) * 64 + l) * 8);
    bfrag8 b2f = *(const bfrag8*)(wU + ((size_t)(nt[2] * 4 + kt) * 64 + l) * 8);
    bfrag8 b3f = *(const bfrag8*)(wU + ((size_t)(nt[3] * 4 + kt) * 64 + l) * 8);
#pragma unroll
    for (int rt = 0; rt < 4; ++rt) {
      bfrag8 zf = *(const bfrag8*)(&zl[(rt * 16 + lm) * 136 + SWC(lm, kt * 32 + lg * 8)]);
      acc[rt][0] = mfma_bf16(zf, b0, acc[rt][0]);
      acc[rt][1] = mfma_bf16(zf, b1, acc[rt][1]);
      acc[rt][2] = mfma_bf16(zf, b2f, acc[rt][2]);
      acc[rt][3] = mfma_bf16(zf, b3f, acc[rt][3]);
    }
  }
#pragma unroll
  for (int rt = 0; rt < 4; ++rt)
#pragma unroll
    for (int j = 0; j < 4; ++j)
#pragma unroll
      for (int i = 0; i < 4; ++i) {
        int r = rt * 16 + rr + i;
        hb[r * 264 + SWC(r, cc[j])] = f2bf(fmaxf(acc[rt][j][i], 0.f));
      }
  __syncthreads();
  // ---- layer 2 ----
  facc4 a2[4][4];
#pragma unroll
  for (int rt = 0; rt < 4; ++rt)
#pragma unroll
    for (int j = 0; j < 4; ++j) a2[rt][j] = (facc4){pb2[nt[j] * 16 + lm], pb2[nt[j] * 16 + lm],
                                                    pb2[nt[j] * 16 + lm], pb2[nt[j] * 16 + lm]};
#pragma unroll
  for (int kt = 0; kt < 8; ++kt) {
    bfrag8 b0 = *(const bfrag8*)(w2p + ((size_t)(nt[0] * 8 + kt) * 64 + l) * 8);
    bfrag8 b1 = *(const bfrag8*)(w2p + ((size_t)(nt[1] * 8 + kt) * 64 + l) * 8);
    bfrag8 b2f = *(const bfrag8*)(w2p + ((size_t)(nt[2] * 8 + kt) * 64 + l) * 8);
    bfrag8 b3f = *(const bfrag8*)(w2p + ((size_t)(nt[3] * 8 + kt) * 64 + l) * 8);
#pragma unroll
    for (int rt = 0; rt < 4; ++rt) {
      bfrag8 hf = *(const bfrag8*)(&hb[(rt * 16 + lm) * 264 + SWC(lm, kt * 32 + lg * 8)]);
      a2[rt][0] = mfma_bf16(hf, b0, a2[rt][0]);
      a2[rt][1] = mfma_bf16(hf, b1, a2[rt][1]);
      a2[rt][2] = mfma_bf16(hf, b2f, a2[rt][2]);
      a2[rt][3] = mfma_bf16(hf, b3f, a2[rt][3]);
    }
  }
  __syncthreads();
#pragma unroll
  for (int rt = 0; rt < 4; ++rt)
#pragma unroll
    for (int j = 0; j < 4; ++j)
#pragma unroll
      for (int i = 0; i < 4; ++i) {
        int r = rt * 16 + rr + i;
        hb[r * 264 + SWC(r, cc[j])] = f2bf(fmaxf(a2[rt][j][i], 0.f));
      }
  __syncthreads();
  // ---- layer 3 ----
  facc4 a3[4][4];
#pragma unroll
  for (int rt = 0; rt < 4; ++rt)
#pragma unroll
    for (int j = 0; j < 4; ++j) a3[rt][j] = (facc4){pb3[nt[j] * 16 + lm], pb3[nt[j] * 16 + lm],
                                                    pb3[nt[j] * 16 + lm], pb3[nt[j] * 16 + lm]};
#pragma unroll
  for (int kt = 0; kt < 8; ++kt) {
    bfrag8 b0 = *(const bfrag8*)(w3p + ((size_t)(nt[0] * 8 + kt) * 64 + l) * 8);
    bfrag8 b1 = *(const bfrag8*)(w3p + ((size_t)(nt[1] * 8 + kt) * 64 + l) * 8);
    bfrag8 b2f = *(const bfrag8*)(w3p + ((size_t)(nt[2] * 8 + kt) * 64 + l) * 8);
    bfrag8 b3f = *(const bfrag8*)(w3p + ((size_t)(nt[3] * 8 + kt) * 64 + l) * 8);
#pragma unroll
    for (int rt = 0; rt < 4; ++rt) {
      bfrag8 hf = *(const bfrag8*)(&hb[(rt * 16 + lm) * 264 + SWC(lm, kt * 32 + lg * 8)]);
      a3[rt][0] = mfma_bf16(hf, b0, a3[rt][0]);
      a3[rt][1] = mfma_bf16(hf, b1, a3[rt][1]);
      a3[rt][2] = mfma_bf16(hf, b2f, a3[rt][2]);
      a3[rt][3] = mfma_bf16(hf, b3f, a3[rt][3]);
    }
  }
#pragma unroll
  for (int rt = 0; rt < 4; ++rt)
#pragma unroll
    for (int i = 0; i < 4; ++i) {
      size_t base = ((size_t)(gp * 64 + rt * 16 + rr + i) * 256 + s) * 128;
      pm_o[base + c0]  = a3[rt][0][i];
      pm_o[base + c1]  = a3[rt][1][i];
      plv_o[base + c0] = a3[rt][2][i];
      plv_o[base + c1] = a3[rt][3][i];
    }
}

// ---------------------------------------------------------------------------
// mega2: k2 (64 blocks, FIRST) + k3 (4096 blocks, s-major). 512 threads.
// 84 KB dynamic LDS -> 1 block/CU: k2 owns its CUs exclusively.
// ---------------------------------------------------------------------------
__global__ __launch_bounds__(512, 2) void mega2(
    const float* __restrict__ prevz, const float* __restrict__ eps,
    const unsigned short* __restrict__ Uq, const unsigned short* __restrict__ W2q,
    const unsigned short* __restrict__ W3q, const unsigned short* __restrict__ Up,
    const unsigned short* __restrict__ W2p, const unsigned short* __restrict__ W3p,
    const float* __restrict__ qb2, const float* __restrict__ qb3,
    const float* __restrict__ pb1, const float* __restrict__ pb2,
    const float* __restrict__ pb3,
    const unsigned int* __restrict__ cq, const unsigned short* __restrict__ cp,
    float* z_o, float* qm_o, float* qlv_o, float* pm_o, float* plv_o,
    int* zdone) {
  extern __shared__ __align__(16) char smem[];
  const int bid = blockIdx.x;
  const int tid = threadIdx.x;
  if (bid < 64) {
    unsigned short* zl = (unsigned short*)smem;
    unsigned short* h1 = zl + 16 * 136;
    unsigned short* h2 = h1 + 16 * 264;
    k2_body<1>(bid, tid, zl, h1, h2, prevz, eps, Uq, W2q, W3q, qb2, qb3, cq,
               z_o, qm_o, qlv_o, zdone);
  } else {
    if (tid >= 256) return;
    const int b2 = bid - 64;
    const int s = b2 >> 4, gp = b2 & 15;
    unsigned short* zl = (unsigned short*)smem;
    unsigned short* hb = zl + 64 * 136;
    k3_body<1>(gp, s, tid, zl, hb, prevz, z_o, cp, Up, W2p, W3p,
               pb1, pb2, pb3, pm_o, plv_o, zdone);
  }
}

// ---------------------------------------------------------------------------
// Fallback sequential kernels (if attribute set fails or ws too small).
// ---------------------------------------------------------------------------
__global__ __launch_bounds__(512, 2) void k2_scan(
    const float* __restrict__ prevz, const float* __restrict__ eps,
    const unsigned short* __restrict__ wU, const unsigned short* __restrict__ wW2,
    const unsigned short* __restrict__ wW3,
    const float* __restrict__ qb2, const float* __restrict__ qb3,
    const unsigned int* __restrict__ cq,
    float* __restrict__ z_o, float* __restrict__ qm_o, float* __restrict__ qlv_o) {
  __shared__ unsigned short zl[16 * 136];
  __shared__ unsigned short h1[16 * 264];
  __shared__ unsigned short h2[16 * 264];
  k2_body<0>(blockIdx.x, threadIdx.x, zl, h1, h2, prevz, eps, wU, wW2, wW3,
             qb2, qb3, cq, z_o, qm_o, qlv_o, nullptr);
}
__global__ __launch_bounds__(256, 2) void k3_prior(
    const float* __restrict__ prevz, const float* __restrict__ z_in,
    const unsigned short* __restrict__ cp,
    const unsigned short* __restrict__ wU, const unsigned short* __restrict__ w2p,
    const unsigned short* __restrict__ w3p,
    const float* __restrict__ pb1, const float* __restrict__ pb2,
    const float* __restrict__ pb3,
    float* __restrict__ pm_o, float* __restrict__ plv_o) {
  __shared__ unsigned short zl[64 * 136];
  __shared__ unsigned short hb[64 * 264];
  k3_body<0>(blockIdx.x >> 8, blockIdx.x & 255, threadIdx.x, zl, hb,
             prevz, z_in, cp, wU, w2p, w3p, pb1, pb2, pb3, pm_o, plv_o,
             nullptr);
}

// ---------------------------------------------------------------------------
extern "C" void kernel_launch(void* const* d_in, const int* in_sizes, int n_in,
                              void* d_out, int out_size, void* d_ws, size_t ws_size,
                              hipStream_t stream) {
  const float* enc   = (const float*)d_in[0];
  const float* prevz = (const float*)d_in[1];
  const float* eps   = (const float*)d_in[2];
  const float* pW1 = (const float*)d_in[3];
  const float* pb1 = (const float*)d_in[4];
  const float* pW2 = (const float*)d_in[5];
  const float* pb2 = (const float*)d_in[6];
  const float* pW3 = (const float*)d_in[7];
  const float* pb3 = (const float*)d_in[8];
  const float* qW1 = (const float*)d_in[9];
  const float* qb1 = (const float*)d_in[10];
  const float* qW2 = (const float*)d_in[11];
  const float* qb2 = (const float*)d_in[12];
  const float* qW3 = (const float*)d_in[13];
  const float* qb3 = (const float*)d_in[14];

  float* out = (float*)d_out;
  const size_t O = (size_t)1024 * 256 * 128;
  float* z_o   = out;
  float* pm_o  = out + O;
  float* plv_o = out + 2 * O;
  float* qm_o  = out + 3 * O;
  float* qlv_o = out + 4 * O;
  unsigned int*   cq = (unsigned int*)qm_o;     // row-aligned Cq pairs (k2 input;
                                                // k2 itself overwrites with qm)
  unsigned short* cp = (unsigned short*)plv_o;  // row-aligned Cp (k3 input)

  unsigned short* ws = (unsigned short*)d_ws;
  unsigned short* Wqe  = ws;             // 65536
  unsigned short* Uq   = ws + 65536;     // 32768
  unsigned short* W2q  = ws + 98304;     // 65536
  unsigned short* W3q  = ws + 163840;    // 65536
  unsigned short* W1ph = ws + 229376;    // 65536
  unsigned short* Up   = ws + 294912;    // 32768
  unsigned short* W2p  = ws + 327680;    // 65536
  unsigned short* W3p  = ws + 393216;    // 65536 (weights end: 458752 shorts)

  const size_t FLAGS_OFF = 458752u * 2u;          // bytes
  int* zdone = (int*)((char*)d_ws + FLAGS_OFF);   // 64 ints (per k2 group)
  const int MEGA_LDS = 86016;                     // 84 KB -> 1 block/CU
  bool fused = ws_size >= FLAGS_OFF + 64 * sizeof(int);
  if (fused &&
      hipFuncSetAttribute((const void*)mega2,
                          hipFuncAttributeMaxDynamicSharedMemorySize,
                          MEGA_LDS) != hipSuccess)
    fused = false;

  pack_all<<<224, 256, 0, stream>>>(qW1, qW2, qW3, pW1, pW2, pW3, ws);
  k1_pre<<<8192, 256, 0, stream>>>(enc, Wqe, W1ph, qb1, cq, cp);
  if (fused) {
    hipMemsetAsync(zdone, 0, 64 * sizeof(int), stream);
    mega2<<<4160, 512, MEGA_LDS, stream>>>(prevz, eps, Uq, W2q, W3q,
                                           Up, W2p, W3p,
                                           qb2, qb3, pb1, pb2, pb3,
                                           cq, cp, z_o, qm_o, qlv_o, pm_o, plv_o,
                                           zdone);
  } else {
    k2_scan<<<64, 512, 0, stream>>>(prevz, eps, Uq, W2q, W3q, qb2, qb3, cq,
                                    z_o, qm_o, qlv_o);
    k3_prior<<<4096, 256, 0, stream>>>(prevz, z_o, cp, Up, W2p, W3p,
                                       pb1, pb2, pb3, pm_o, plv_o);
  }
}